// Round 1
// baseline (1613.964 us; speedup 1.0000x reference)
//
#include <hip/hip_runtime.h>
#include <math.h>

// Problem constants (from reference): B=2, S=2048, D=1024, H=16, DQ=64
#define BB 2
#define SS 2048
#define DD 1024
#define HH 16
#define DQK 64
#define NROWS (BB * SS)                 // 4096 token rows
#define NE ((size_t)BB * SS * DD)       // 4,194,304 elements per [B,S,D] buffer

// ---------------------------------------------------------------------------
// LayerNorm: one block (256 threads) per token row. float4 loads, wave+block
// reduce for mean/var (biased), eps inside rsqrt — matches torch/jax ref.
// ---------------------------------------------------------------------------
__global__ __launch_bounds__(256) void ln_fwd(const float* __restrict__ x,
                                              const float* __restrict__ g,
                                              const float* __restrict__ bta,
                                              float* __restrict__ xn) {
  const int row = blockIdx.x;
  const int t = threadIdx.x;
  float4 v = ((const float4*)(x + (size_t)row * DD))[t];
  float s  = v.x + v.y + v.z + v.w;
  float ss = v.x * v.x + v.y * v.y + v.z * v.z + v.w * v.w;
#pragma unroll
  for (int off = 32; off > 0; off >>= 1) {
    s  += __shfl_xor(s, off);
    ss += __shfl_xor(ss, off);
  }
  __shared__ float red[8];
  const int wid = t >> 6, lane = t & 63;
  if (lane == 0) { red[wid] = s; red[4 + wid] = ss; }
  __syncthreads();
  const float stot  = red[0] + red[1] + red[2] + red[3];
  const float sstot = red[4] + red[5] + red[6] + red[7];
  const float mu  = stot * (1.0f / DD);
  const float var = sstot * (1.0f / DD) - mu * mu;
  const float inv = rsqrtf(var + 1e-5f);
  const float4 g4 = ((const float4*)g)[t];
  const float4 b4 = ((const float4*)bta)[t];
  float4 o;
  o.x = (v.x - mu) * inv * g4.x + b4.x;
  o.y = (v.y - mu) * inv * g4.y + b4.y;
  o.z = (v.z - mu) * inv * g4.z + b4.z;
  o.w = (v.w - mu) * inv * g4.w + b4.w;
  ((float4*)(xn + (size_t)row * DD))[t] = o;
}

// ---------------------------------------------------------------------------
// fp32 GEMM: C[M,N] = A[M,K] @ W[K,N] + bias (+ residual). M=4096, N=K=1024.
// 64x64 block tile, BK=16, 256 threads, 4x4 microtile per thread.
// ---------------------------------------------------------------------------
#define GBM 64
#define GBN 64
#define GBK 16
#define GM NROWS
#define GN DD
#define GK DD

__global__ __launch_bounds__(256) void gemm_bias(const float* __restrict__ A,
                                                 const float* __restrict__ W,
                                                 const float* __restrict__ bias,
                                                 const float* __restrict__ resid,
                                                 float* __restrict__ C) {
  __shared__ float As[GBK][GBM];  // transposed A tile: As[k][m]
  __shared__ float Bs[GBK][GBN];
  const int t = threadIdx.x;
  const int row0 = blockIdx.x * GBM;
  const int col0 = blockIdx.y * GBN;
  const int tx = t & 15, ty = t >> 4;
  const int ar = t >> 2, ak = (t & 3) << 2;   // A load: row0+ar, k0+ak..ak+3
  const int br = t >> 4, bc = (t & 15) << 2;  // B load: k0+br, col0+bc..bc+3
  float acc[4][4] = {{0.f}};
  const float* Aptr = A + (size_t)(row0 + ar) * GK + ak;
  const float* Wptr = W + (size_t)br * GN + col0 + bc;

  for (int k0 = 0; k0 < GK; k0 += GBK) {
    const float4 a4 = *(const float4*)(Aptr + k0);
    const float4 b4 = *(const float4*)(Wptr + (size_t)k0 * GN);
    As[ak + 0][ar] = a4.x;
    As[ak + 1][ar] = a4.y;
    As[ak + 2][ar] = a4.z;
    As[ak + 3][ar] = a4.w;
    *(float4*)&Bs[br][bc] = b4;
    __syncthreads();
#pragma unroll
    for (int kk = 0; kk < GBK; ++kk) {
      const float4 a = *(const float4*)&As[kk][ty * 4];
      const float4 b = *(const float4*)&Bs[kk][tx * 4];
      acc[0][0] += a.x * b.x; acc[0][1] += a.x * b.y; acc[0][2] += a.x * b.z; acc[0][3] += a.x * b.w;
      acc[1][0] += a.y * b.x; acc[1][1] += a.y * b.y; acc[1][2] += a.y * b.z; acc[1][3] += a.y * b.w;
      acc[2][0] += a.z * b.x; acc[2][1] += a.z * b.y; acc[2][2] += a.z * b.z; acc[2][3] += a.z * b.w;
      acc[3][0] += a.w * b.x; acc[3][1] += a.w * b.y; acc[3][2] += a.w * b.z; acc[3][3] += a.w * b.w;
    }
    __syncthreads();
  }

#pragma unroll
  for (int i = 0; i < 4; ++i) {
    const int r = row0 + ty * 4 + i;
    const int c = col0 + tx * 4;
    const float4 bi = *(const float4*)(bias + c);
    float4 o;
    o.x = acc[i][0] + bi.x;
    o.y = acc[i][1] + bi.y;
    o.z = acc[i][2] + bi.z;
    o.w = acc[i][3] + bi.w;
    if (resid) {
      const float4 rx = *(const float4*)(resid + (size_t)r * GN + c);
      o.x += rx.x; o.y += rx.y; o.z += rx.z; o.w += rx.w;
    }
    *(float4*)(C + (size_t)r * GN + c) = o;
  }
}

// ---------------------------------------------------------------------------
// Causal flash attention, fp32. One wave (64 lanes) per 16 query rows of one
// (b,h). lane == head-dim index (DQ=64). Per 64-key tile:
//   phase A: lane j computes scores for all 16 rows (K row per lane, Q from
//            LDS broadcast); per-row wave-max/sum via shfl; P -> LDS.
//   phase B: lane d accumulates acc[r] += P[r][jj] * V[jj][d] (coalesced V).
// ---------------------------------------------------------------------------
#define QT 16

__global__ __launch_bounds__(64) void attn_fwd(const float* __restrict__ Q,
                                               const float* __restrict__ K,
                                               const float* __restrict__ V,
                                               float* __restrict__ O) {
  const int lane = threadIdx.x;
  const int blk = blockIdx.x;                // 0 .. B*H*(S/QT)-1
  const int qb = blk & (SS / QT - 1);
  const int bh = blk / (SS / QT);
  const int q0 = qb * QT;
  const int b = bh / HH;
  const int h = bh % HH;
  const size_t base = (size_t)b * SS * DD + (size_t)h * DQK;  // offset at s=0

  __shared__ float q_lds[QT][DQK];
  __shared__ float p_lds[QT][DQK];

#pragma unroll
  for (int r = 0; r < QT; ++r)
    q_lds[r][lane] = Q[base + (size_t)(q0 + r) * DD + lane];
  __syncthreads();

  float m[QT], l[QT], acc[QT];
#pragma unroll
  for (int r = 0; r < QT; ++r) { m[r] = -INFINITY; l[r] = 0.f; acc[r] = 0.f; }

  const int qmax = q0 + QT - 1;
  for (int j0 = 0; j0 <= qmax; j0 += 64) {
    const int j = j0 + lane;  // key index owned by this lane (always < S)
    float sc[QT];
#pragma unroll
    for (int r = 0; r < QT; ++r) sc[r] = 0.f;
    const float* kr = K + base + (size_t)j * DD;
#pragma unroll
    for (int d = 0; d < DQK; d += 4) {
      const float4 k4 = *(const float4*)(kr + d);
#pragma unroll
      for (int r = 0; r < QT; ++r) {
        const float4 q4 = *(const float4*)&q_lds[r][d];
        sc[r] += q4.x * k4.x + q4.y * k4.y + q4.z * k4.z + q4.w * k4.w;
      }
    }
#pragma unroll
    for (int r = 0; r < QT; ++r) {
      // causal mask: keep j <= q0+r. First tile always has lane 0 valid, so
      // mnew is finite from tile 0 onward (no inf-inf NaN path).
      const float s = (j <= q0 + r) ? sc[r] * 0.125f : -INFINITY;  // 1/sqrt(64)
      float tm = s;
#pragma unroll
      for (int off = 32; off > 0; off >>= 1) tm = fmaxf(tm, __shfl_xor(tm, off));
      const float mnew = fmaxf(m[r], tm);
      const float escale = __expf(m[r] - mnew);
      const float p = __expf(s - mnew);
      float ps = p;
#pragma unroll
      for (int off = 32; off > 0; off >>= 1) ps += __shfl_xor(ps, off);
      l[r] = l[r] * escale + ps;
      acc[r] *= escale;
      m[r] = mnew;
      p_lds[r][lane] = p;
    }
    __syncthreads();
    const float* vb = V + base + (size_t)j0 * DD + lane;
    for (int jj = 0; jj < 64; jj += 4) {
      const float v0 = vb[(size_t)(jj + 0) * DD];
      const float v1 = vb[(size_t)(jj + 1) * DD];
      const float v2 = vb[(size_t)(jj + 2) * DD];
      const float v3 = vb[(size_t)(jj + 3) * DD];
#pragma unroll
      for (int r = 0; r < QT; ++r) {
        const float4 p4 = *(const float4*)&p_lds[r][jj];
        acc[r] += p4.x * v0 + p4.y * v1 + p4.z * v2 + p4.w * v3;
      }
    }
    __syncthreads();
  }

#pragma unroll
  for (int r = 0; r < QT; ++r)
    O[base + (size_t)(q0 + r) * DD + lane] = acc[r] / l[r];
}

// ---------------------------------------------------------------------------
// Launch: LN -> 3x GEMM (Q,K,V) -> attention -> output GEMM (+bias+residual).
// Workspace: 4 x 16 MB fp32 buffers (xn reused for attention output).
// ---------------------------------------------------------------------------
extern "C" void kernel_launch(void* const* d_in, const int* in_sizes, int n_in,
                              void* d_out, int out_size, void* d_ws, size_t ws_size,
                              hipStream_t stream) {
  const float* x    = (const float*)d_in[0];
  const float* ln_g = (const float*)d_in[1];
  const float* ln_b = (const float*)d_in[2];
  const float* Wq   = (const float*)d_in[3];
  const float* bq   = (const float*)d_in[4];
  const float* Wk   = (const float*)d_in[5];
  const float* bk   = (const float*)d_in[6];
  const float* Wv   = (const float*)d_in[7];
  const float* bv   = (const float*)d_in[8];
  const float* Wo   = (const float*)d_in[9];
  const float* bo   = (const float*)d_in[10];
  float* out = (float*)d_out;

  float* ws = (float*)d_ws;
  float* xn = ws;            // [B*S, D]; reused as attention output
  float* q  = ws + NE;
  float* k  = ws + 2 * NE;
  float* v  = ws + 3 * NE;
  float* att = xn;           // attention output overwrites xn (no longer needed)

  ln_fwd<<<NROWS, 256, 0, stream>>>(x, ln_g, ln_b, xn);

  dim3 gg(GM / GBM, GN / GBN);  // (64, 16)
  gemm_bias<<<gg, 256, 0, stream>>>(xn, Wq, bq, nullptr, q);
  gemm_bias<<<gg, 256, 0, stream>>>(xn, Wk, bk, nullptr, k);
  gemm_bias<<<gg, 256, 0, stream>>>(xn, Wv, bv, nullptr, v);

  attn_fwd<<<BB * HH * (SS / QT), 64, 0, stream>>>(q, k, v, att);

  gemm_bias<<<gg, 256, 0, stream>>>(att, Wo, bo, x, out);
}

// Round 2
// 337.065 us; speedup vs baseline: 4.7883x; 4.7883x over previous
//
#include <hip/hip_runtime.h>
#include <math.h>

// Problem constants: B=2, S=2048, D=1024, H=16, DQ=64
#define BB 2
#define SS 2048
#define DD 1024
#define HH 16
#define DQK 64
#define NROWS (BB * SS)
#define NE ((size_t)BB * SS * DD)   // 4,194,304

using short8 = __attribute__((ext_vector_type(8))) short;
using f32x4  = __attribute__((ext_vector_type(4))) float;

__device__ __forceinline__ ushort f2bf(float f) {
  union { float f; unsigned u; } c; c.f = f;
  return (ushort)((c.u + 0x7fffu + ((c.u >> 16) & 1u)) >> 16);
}

__device__ __forceinline__ f32x4 mfma16(short8 a, short8 b, f32x4 c) {
  return __builtin_amdgcn_mfma_f32_16x16x32_bf16(a, b, c, 0, 0, 0);
}

// ---------------------------------------------------------------------------
// LayerNorm -> bf16. One block per row.
// ---------------------------------------------------------------------------
__global__ __launch_bounds__(256) void ln_fwd(const float* __restrict__ x,
                                              const float* __restrict__ g,
                                              const float* __restrict__ bta,
                                              ushort* __restrict__ xn) {
  const int row = blockIdx.x;
  const int t = threadIdx.x;
  float4 v = ((const float4*)(x + (size_t)row * DD))[t];
  float s  = v.x + v.y + v.z + v.w;
  float ss = v.x * v.x + v.y * v.y + v.z * v.z + v.w * v.w;
#pragma unroll
  for (int off = 32; off > 0; off >>= 1) {
    s  += __shfl_xor(s, off);
    ss += __shfl_xor(ss, off);
  }
  __shared__ float red[8];
  const int wid = t >> 6, lane = t & 63;
  if (lane == 0) { red[wid] = s; red[4 + wid] = ss; }
  __syncthreads();
  const float stot  = red[0] + red[1] + red[2] + red[3];
  const float sstot = red[4] + red[5] + red[6] + red[7];
  const float mu  = stot * (1.0f / DD);
  const float var = sstot * (1.0f / DD) - mu * mu;
  const float inv = rsqrtf(var + 1e-5f);
  const float4 g4 = ((const float4*)g)[t];
  const float4 b4 = ((const float4*)bta)[t];
  ushort4 o;
  o.x = f2bf((v.x - mu) * inv * g4.x + b4.x);
  o.y = f2bf((v.y - mu) * inv * g4.y + b4.y);
  o.z = f2bf((v.z - mu) * inv * g4.z + b4.z);
  o.w = f2bf((v.w - mu) * inv * g4.w + b4.w);
  ((ushort4*)(xn + (size_t)row * DD))[t] = o;
}

// ---------------------------------------------------------------------------
// Transpose + bf16-cast the 4 weight matrices: W[K][N] fp32 -> Wt[N][K] bf16.
// 64x64 tiles, LDS padded [64][65].
// ---------------------------------------------------------------------------
__global__ __launch_bounds__(256) void wtrans(const float* __restrict__ Wq,
                                              const float* __restrict__ Wk,
                                              const float* __restrict__ Wv,
                                              const float* __restrict__ Wo,
                                              ushort* __restrict__ wt) {
  const int z = blockIdx.z;
  const float* W = (z == 0) ? Wq : (z == 1) ? Wk : (z == 2) ? Wv : Wo;
  ushort* dst = wt + (size_t)z * DD * DD;
  __shared__ float tile[64][65];
  const int t = threadIdx.x;
  const int k0 = blockIdx.x * 64, n0 = blockIdx.y * 64;
  const int tr = t >> 4, tc = (t & 15) * 4;
#pragma unroll
  for (int rr = 0; rr < 64; rr += 16) {
    float4 v = *(const float4*)(W + (size_t)(k0 + rr + tr) * DD + n0 + tc);
    tile[rr + tr][tc + 0] = v.x;
    tile[rr + tr][tc + 1] = v.y;
    tile[rr + tr][tc + 2] = v.z;
    tile[rr + tr][tc + 3] = v.w;
  }
  __syncthreads();
#pragma unroll
  for (int rr = 0; rr < 64; rr += 16) {
    const int n = rr + tr;
    ushort4 o;
    o.x = f2bf(tile[tc + 0][n]);
    o.y = f2bf(tile[tc + 1][n]);
    o.z = f2bf(tile[tc + 2][n]);
    o.w = f2bf(tile[tc + 3][n]);
    *(ushort4*)(dst + (size_t)(n0 + n) * DD + k0 + tc) = o;
  }
}

// ---------------------------------------------------------------------------
// bf16 MFMA GEMM: C[M=4096][N=1024] = A[M][K=1024] @ Wt[N][K]^T + bias.
// 128x128 tile, 4 waves (2x2), 4x4 16x16 frags/wave, BK=32, reg-staged LDS.
// MODE 0: bf16 out [M][N]. MODE 1: bf16 out transposed per-head to Vt.
// MODE 2: fp32 out [M][N] + residual.
// ---------------------------------------------------------------------------
template <int MODE>
__global__ __launch_bounds__(256) void gemm_mfma(
    const ushort* __restrict__ A, const ushort* __restrict__ Bt,
    const float* __restrict__ bias, const float* __restrict__ resid,
    ushort* __restrict__ outb, float* __restrict__ outf) {
  __shared__ ushort As[128][32];
  __shared__ ushort Bs[128][32];
  const int t = threadIdx.x;
  const int lane = t & 63;
  const int w = t >> 6, wr = w >> 1, wc = w & 1;
  const int r16 = lane & 15, g = lane >> 4;
  const int row0 = blockIdx.x * 128, col0 = blockIdx.y * 128;

  f32x4 acc[4][4];
#pragma unroll
  for (int m = 0; m < 4; ++m)
#pragma unroll
    for (int n = 0; n < 4; ++n) acc[m][n] = (f32x4){0.f, 0.f, 0.f, 0.f};

  const int srow = t >> 2, skc = (t & 3) * 8;
  const ushort* Ap = A + (size_t)(row0 + srow) * DD + skc;
  const ushort* Bp = Bt + (size_t)(col0 + srow) * DD + skc;

  for (int k0 = 0; k0 < DD; k0 += 32) {
    short8 a0 = *(const short8*)(Ap + k0);
    short8 a1 = *(const short8*)(Ap + (size_t)64 * DD + k0);
    short8 b0 = *(const short8*)(Bp + k0);
    short8 b1 = *(const short8*)(Bp + (size_t)64 * DD + k0);
    __syncthreads();  // previous iter's frag reads done before overwrite
    *(short8*)&As[srow][skc] = a0;
    *(short8*)&As[srow + 64][skc] = a1;
    *(short8*)&Bs[srow][skc] = b0;
    *(short8*)&Bs[srow + 64][skc] = b1;
    __syncthreads();
    short8 af[4], bf[4];
#pragma unroll
    for (int m = 0; m < 4; ++m) af[m] = *(const short8*)&As[wr * 64 + m * 16 + r16][g * 8];
#pragma unroll
    for (int n = 0; n < 4; ++n) bf[n] = *(const short8*)&Bs[wc * 64 + n * 16 + r16][g * 8];
#pragma unroll
    for (int m = 0; m < 4; ++m)
#pragma unroll
      for (int n = 0; n < 4; ++n) acc[m][n] = mfma16(af[m], bf[n], acc[m][n]);
  }

#pragma unroll
  for (int n = 0; n < 4; ++n) {
    const int c = col0 + wc * 64 + n * 16 + r16;
    const float bc = bias[c];
#pragma unroll
    for (int m = 0; m < 4; ++m) {
      const int rbase = row0 + wr * 64 + m * 16 + g * 4;
      if (MODE == 0) {
#pragma unroll
        for (int e = 0; e < 4; ++e)
          outb[(size_t)(rbase + e) * DD + c] = f2bf(acc[m][n][e] + bc);
      } else if (MODE == 1) {
        // Vt[(b*H + h)*DQ + dq][s] ; h=c>>6, dq=c&63, b=rbase>>11, s=rbase&2047
        ushort4 st;
        st.x = f2bf(acc[m][n][0] + bc);
        st.y = f2bf(acc[m][n][1] + bc);
        st.z = f2bf(acc[m][n][2] + bc);
        st.w = f2bf(acc[m][n][3] + bc);
        const size_t vrow = (size_t)((rbase >> 11) * HH + (c >> 6)) * DQK + (c & 63);
        *(ushort4*)(outb + vrow * SS + (rbase & 2047)) = st;
      } else {
#pragma unroll
        for (int e = 0; e < 4; ++e) {
          const size_t idx = (size_t)(rbase + e) * DD + c;
          outf[idx] = acc[m][n][e] + bc + resid[idx];
        }
      }
    }
  }
}

// ---------------------------------------------------------------------------
// MFMA flash attention (causal). 4 waves/block, 1 wave per 16 q-rows.
// Per 32-key chunk: 2 QK^T MFMAs, online softmax (16-lane shfl reduces),
// P->bf16 via padded per-wave LDS round-trip, 4 PV MFMAs vs Vt.
// q-tiles mapped descending for load balance; XCD-swizzled block ids.
// ---------------------------------------------------------------------------
__global__ __launch_bounds__(256) void attn_mfma(const ushort* __restrict__ Q,
                                                 const ushort* __restrict__ K,
                                                 const ushort* __restrict__ Vt,
                                                 ushort* __restrict__ O) {
  __shared__ ushort p_all[4][16][40];  // per-wave P tile, padded rows (80B)
  const int t = threadIdx.x, lane = t & 63, ww = t >> 6;
  int bid = blockIdx.x;
  bid = (bid & 7) * 128 + (bid >> 3);       // 1024 = 8*128, bijective
  const int gw = bid * 4 + ww;
  const int bh = gw >> 7;                    // 0..31
  const int qt = 127 - (gw & 127);           // descending work size
  const int b = bh >> 4, h = bh & 15;
  const int q0 = qt * 16;
  const int r16 = lane & 15, g = lane >> 4;
  const size_t tokbase = (size_t)b * SS;

  short8 qf[2];
#pragma unroll
  for (int kc = 0; kc < 2; ++kc)
    qf[kc] = *(const short8*)(Q + (tokbase + q0 + r16) * DD + h * DQK + kc * 32 + g * 8);

  f32x4 o[4];
#pragma unroll
  for (int dt = 0; dt < 4; ++dt) o[dt] = (f32x4){0.f, 0.f, 0.f, 0.f};
  float rm[4] = {-INFINITY, -INFINITY, -INFINITY, -INFINITY};
  float rl[4] = {0.f, 0.f, 0.f, 0.f};

  for (int j0 = 0; j0 <= q0 + 15; j0 += 32) {
    short8 kf[2][2];
#pragma unroll
    for (int t2 = 0; t2 < 2; ++t2)
#pragma unroll
      for (int kc = 0; kc < 2; ++kc)
        kf[t2][kc] = *(const short8*)(K + (tokbase + j0 + t2 * 16 + r16) * DD +
                                      h * DQK + kc * 32 + g * 8);
    short8 vf[4];
#pragma unroll
    for (int dt = 0; dt < 4; ++dt)
      vf[dt] = *(const short8*)(Vt + ((size_t)bh * DQK + dt * 16 + r16) * SS + j0 + g * 8);

    f32x4 sacc[2];
#pragma unroll
    for (int t2 = 0; t2 < 2; ++t2) {
      sacc[t2] = mfma16(qf[0], kf[t2][0], (f32x4){0.f, 0.f, 0.f, 0.f});
      sacc[t2] = mfma16(qf[1], kf[t2][1], sacc[t2]);
    }
    float sv[2][4];
#pragma unroll
    for (int t2 = 0; t2 < 2; ++t2)
#pragma unroll
      for (int r = 0; r < 4; ++r) {
        const int col = j0 + t2 * 16 + r16;
        const int row = q0 + g * 4 + r;
        sv[t2][r] = (col <= row) ? sacc[t2][r] * 0.125f : -INFINITY;
      }

#pragma unroll
    for (int r = 0; r < 4; ++r) {
      float mx = fmaxf(sv[0][r], sv[1][r]);
#pragma unroll
      for (int off = 1; off < 16; off <<= 1) mx = fmaxf(mx, __shfl_xor(mx, off));
      const float mn = fmaxf(rm[r], mx);
      const float sc = __expf(rm[r] - mn);
      const float p0 = __expf(sv[0][r] - mn);
      const float p1 = __expf(sv[1][r] - mn);
      float ps = p0 + p1;
#pragma unroll
      for (int off = 1; off < 16; off <<= 1) ps += __shfl_xor(ps, off);
      rl[r] = rl[r] * sc + ps;
      rm[r] = mn;
#pragma unroll
      for (int dt = 0; dt < 4; ++dt) o[dt][r] *= sc;
      p_all[ww][g * 4 + r][r16] = f2bf(p0);
      p_all[ww][g * 4 + r][16 + r16] = f2bf(p1);
    }
    const short8 pf = *(const short8*)&p_all[ww][r16][g * 8];
#pragma unroll
    for (int dt = 0; dt < 4; ++dt) o[dt] = mfma16(pf, vf[dt], o[dt]);
  }

#pragma unroll
  for (int dt = 0; dt < 4; ++dt)
#pragma unroll
    for (int r = 0; r < 4; ++r)
      O[(tokbase + q0 + g * 4 + r) * DD + h * DQK + dt * 16 + r16] =
          f2bf(o[dt][r] / rl[r]);
}

// ---------------------------------------------------------------------------
// Launch: wtrans -> LN -> 3x GEMM (Q,K -> bf16; V -> Vt) -> attn -> O-GEMM.
// ws: xn 8MB | q 8MB | k 8MB | vt 8MB | att 8MB | wt 8MB  (48MB)
// ---------------------------------------------------------------------------
extern "C" void kernel_launch(void* const* d_in, const int* in_sizes, int n_in,
                              void* d_out, int out_size, void* d_ws, size_t ws_size,
                              hipStream_t stream) {
  const float* x    = (const float*)d_in[0];
  const float* ln_g = (const float*)d_in[1];
  const float* ln_b = (const float*)d_in[2];
  const float* Wq   = (const float*)d_in[3];
  const float* bq   = (const float*)d_in[4];
  const float* Wk   = (const float*)d_in[5];
  const float* bk   = (const float*)d_in[6];
  const float* Wv   = (const float*)d_in[7];
  const float* bv   = (const float*)d_in[8];
  const float* Wo   = (const float*)d_in[9];
  const float* bo   = (const float*)d_in[10];
  float* out = (float*)d_out;

  ushort* ws  = (ushort*)d_ws;
  ushort* xn  = ws;
  ushort* qb  = xn + NE;
  ushort* kb  = qb + NE;
  ushort* vt  = kb + NE;
  ushort* ab  = vt + NE;
  ushort* wt  = ab + NE;               // 4 x [1024][1024] bf16
  ushort* wqt = wt;
  ushort* wkt = wt + (size_t)DD * DD;
  ushort* wvt = wt + (size_t)2 * DD * DD;
  ushort* wot = wt + (size_t)3 * DD * DD;

  wtrans<<<dim3(16, 16, 4), 256, 0, stream>>>(Wq, Wk, Wv, Wo, wt);
  ln_fwd<<<NROWS, 256, 0, stream>>>(x, ln_g, ln_b, xn);

  dim3 gg(NROWS / 128, DD / 128);  // (32, 8)
  gemm_mfma<0><<<gg, 256, 0, stream>>>(xn, wqt, bq, nullptr, qb, nullptr);
  gemm_mfma<0><<<gg, 256, 0, stream>>>(xn, wkt, bk, nullptr, kb, nullptr);
  gemm_mfma<1><<<gg, 256, 0, stream>>>(xn, wvt, bv, nullptr, vt, nullptr);

  attn_mfma<<<BB * HH * (SS / 16) / 4, 256, 0, stream>>>(qb, kb, vt, ab);

  gemm_mfma<2><<<gg, 256, 0, stream>>>(ab, wot, bo, x, nullptr, out);
}

// Round 3
// 333.783 us; speedup vs baseline: 4.8354x; 1.0098x over previous
//
#include <hip/hip_runtime.h>
#include <math.h>

// Problem constants: B=2, S=2048, D=1024, H=16, DQ=64
#define BB 2
#define SS 2048
#define DD 1024
#define HH 16
#define DQK 64
#define NROWS (BB * SS)
#define NE ((size_t)BB * SS * DD)   // 4,194,304

using short8 = __attribute__((ext_vector_type(8))) short;
using f32x4  = __attribute__((ext_vector_type(4))) float;

__device__ __forceinline__ ushort f2bf(float f) {
  union { float f; unsigned u; } c; c.f = f;
  return (ushort)((c.u + 0x7fffu + ((c.u >> 16) & 1u)) >> 16);
}

__device__ __forceinline__ f32x4 mfma16(short8 a, short8 b, f32x4 c) {
  return __builtin_amdgcn_mfma_f32_16x16x32_bf16(a, b, c, 0, 0, 0);
}

// ---------------------------------------------------------------------------
// LayerNorm -> bf16. One block per row.
// ---------------------------------------------------------------------------
__global__ __launch_bounds__(256) void ln_fwd(const float* __restrict__ x,
                                              const float* __restrict__ g,
                                              const float* __restrict__ bta,
                                              ushort* __restrict__ xn) {
  const int row = blockIdx.x;
  const int t = threadIdx.x;
  float4 v = ((const float4*)(x + (size_t)row * DD))[t];
  float s  = v.x + v.y + v.z + v.w;
  float ss = v.x * v.x + v.y * v.y + v.z * v.z + v.w * v.w;
#pragma unroll
  for (int off = 32; off > 0; off >>= 1) {
    s  += __shfl_xor(s, off);
    ss += __shfl_xor(ss, off);
  }
  __shared__ float red[8];
  const int wid = t >> 6, lane = t & 63;
  if (lane == 0) { red[wid] = s; red[4 + wid] = ss; }
  __syncthreads();
  const float stot  = red[0] + red[1] + red[2] + red[3];
  const float sstot = red[4] + red[5] + red[6] + red[7];
  const float mu  = stot * (1.0f / DD);
  const float var = sstot * (1.0f / DD) - mu * mu;
  const float inv = rsqrtf(var + 1e-5f);
  const float4 g4 = ((const float4*)g)[t];
  const float4 b4 = ((const float4*)bta)[t];
  ushort4 o;
  o.x = f2bf((v.x - mu) * inv * g4.x + b4.x);
  o.y = f2bf((v.y - mu) * inv * g4.y + b4.y);
  o.z = f2bf((v.z - mu) * inv * g4.z + b4.z);
  o.w = f2bf((v.w - mu) * inv * g4.w + b4.w);
  ((ushort4*)(xn + (size_t)row * DD))[t] = o;
}

// ---------------------------------------------------------------------------
// Transpose + bf16-cast the 4 weight matrices: W[K][N] fp32 -> Wt[N][K] bf16.
// ---------------------------------------------------------------------------
__global__ __launch_bounds__(256) void wtrans(const float* __restrict__ Wq,
                                              const float* __restrict__ Wk,
                                              const float* __restrict__ Wv,
                                              const float* __restrict__ Wo,
                                              ushort* __restrict__ wt) {
  const int z = blockIdx.z;
  const float* W = (z == 0) ? Wq : (z == 1) ? Wk : (z == 2) ? Wv : Wo;
  ushort* dst = wt + (size_t)z * DD * DD;
  __shared__ float tile[64][65];
  const int t = threadIdx.x;
  const int k0 = blockIdx.x * 64, n0 = blockIdx.y * 64;
  const int tr = t >> 4, tc = (t & 15) * 4;
#pragma unroll
  for (int rr = 0; rr < 64; rr += 16) {
    float4 v = *(const float4*)(W + (size_t)(k0 + rr + tr) * DD + n0 + tc);
    tile[rr + tr][tc + 0] = v.x;
    tile[rr + tr][tc + 1] = v.y;
    tile[rr + tr][tc + 2] = v.z;
    tile[rr + tr][tc + 3] = v.w;
  }
  __syncthreads();
#pragma unroll
  for (int rr = 0; rr < 64; rr += 16) {
    const int n = rr + tr;
    ushort4 o;
    o.x = f2bf(tile[tc + 0][n]);
    o.y = f2bf(tile[tc + 1][n]);
    o.z = f2bf(tile[tc + 2][n]);
    o.w = f2bf(tile[tc + 3][n]);
    *(ushort4*)(dst + (size_t)(n0 + n) * DD + k0 + tc) = o;
  }
}

// ---------------------------------------------------------------------------
// bf16 MFMA GEMM: C[M=4096][N=1024] = A[M][K=1024] @ Wt[N][K]^T + bias.
// 128x128 tile, 4 waves (2x2), 4x4 16x16 frags/wave, BK=32, reg-staged LDS.
// MODE 0: bf16 out. MODE 1: bf16 out transposed per-head (Vt). MODE 2: fp32+res.
// ---------------------------------------------------------------------------
template <int MODE>
__global__ __launch_bounds__(256) void gemm_mfma(
    const ushort* __restrict__ A, const ushort* __restrict__ Bt,
    const float* __restrict__ bias, const float* __restrict__ resid,
    ushort* __restrict__ outb, float* __restrict__ outf) {
  __shared__ ushort As[128][32];
  __shared__ ushort Bs[128][32];
  const int t = threadIdx.x;
  const int lane = t & 63;
  const int w = t >> 6, wr = w >> 1, wc = w & 1;
  const int r16 = lane & 15, g = lane >> 4;
  const int row0 = blockIdx.x * 128, col0 = blockIdx.y * 128;

  f32x4 acc[4][4];
#pragma unroll
  for (int m = 0; m < 4; ++m)
#pragma unroll
    for (int n = 0; n < 4; ++n) acc[m][n] = (f32x4){0.f, 0.f, 0.f, 0.f};

  const int srow = t >> 2, skc = (t & 3) * 8;
  const ushort* Ap = A + (size_t)(row0 + srow) * DD + skc;
  const ushort* Bp = Bt + (size_t)(col0 + srow) * DD + skc;

  for (int k0 = 0; k0 < DD; k0 += 32) {
    short8 a0 = *(const short8*)(Ap + k0);
    short8 a1 = *(const short8*)(Ap + (size_t)64 * DD + k0);
    short8 b0 = *(const short8*)(Bp + k0);
    short8 b1 = *(const short8*)(Bp + (size_t)64 * DD + k0);
    __syncthreads();
    *(short8*)&As[srow][skc] = a0;
    *(short8*)&As[srow + 64][skc] = a1;
    *(short8*)&Bs[srow][skc] = b0;
    *(short8*)&Bs[srow + 64][skc] = b1;
    __syncthreads();
    short8 af[4], bf[4];
#pragma unroll
    for (int m = 0; m < 4; ++m) af[m] = *(const short8*)&As[wr * 64 + m * 16 + r16][g * 8];
#pragma unroll
    for (int n = 0; n < 4; ++n) bf[n] = *(const short8*)&Bs[wc * 64 + n * 16 + r16][g * 8];
#pragma unroll
    for (int m = 0; m < 4; ++m)
#pragma unroll
      for (int n = 0; n < 4; ++n) acc[m][n] = mfma16(af[m], bf[n], acc[m][n]);
  }

#pragma unroll
  for (int n = 0; n < 4; ++n) {
    const int c = col0 + wc * 64 + n * 16 + r16;
    const float bc = bias[c];
#pragma unroll
    for (int m = 0; m < 4; ++m) {
      const int rbase = row0 + wr * 64 + m * 16 + g * 4;
      if (MODE == 0) {
#pragma unroll
        for (int e = 0; e < 4; ++e)
          outb[(size_t)(rbase + e) * DD + c] = f2bf(acc[m][n][e] + bc);
      } else if (MODE == 1) {
        ushort4 st;
        st.x = f2bf(acc[m][n][0] + bc);
        st.y = f2bf(acc[m][n][1] + bc);
        st.z = f2bf(acc[m][n][2] + bc);
        st.w = f2bf(acc[m][n][3] + bc);
        const size_t vrow = (size_t)((rbase >> 11) * HH + (c >> 6)) * DQK + (c & 63);
        *(ushort4*)(outb + vrow * SS + (rbase & 2047)) = st;
      } else {
#pragma unroll
        for (int e = 0; e < 4; ++e) {
          const size_t idx = (size_t)(rbase + e) * DD + c;
          outf[idx] = acc[m][n][e] + bc + resid[idx];
        }
      }
    }
  }
}

// ---------------------------------------------------------------------------
// MFMA flash attention (causal), SWAPPED-operand form. 4 waves/block, 1 wave
// per 16 q-rows, KVBLK=64. mfma(K,Q) -> S[key][q]: q = lane&15 (lane-resident),
// 16 key-values in regs per 64-key block. Softmax: in-lane tree + 2 shuffles.
// P -> bf16 via padded per-wave LDS tile -> PV B-operand; mfma(Vt,P) -> O[dq][q].
// ---------------------------------------------------------------------------
__global__ __launch_bounds__(256) void attn_mfma(const ushort* __restrict__ Q,
                                                 const ushort* __restrict__ K,
                                                 const ushort* __restrict__ Vt,
                                                 ushort* __restrict__ O) {
  __shared__ ushort p_lds[4][16][72];  // [wave][q][key], padded row = 144B
  const int t = threadIdx.x, lane = t & 63, ww = t >> 6;
  int bid = blockIdx.x;
  bid = (bid & 7) * 128 + (bid >> 3);       // XCD swizzle: 4 heads per XCD
  const int gw = bid * 4 + ww;
  const int bh = gw >> 7;                    // 0..31
  const int qt = 127 - (gw & 127);           // descending work map
  const int b = bh >> 4, h = bh & 15;
  const int q0 = qt * 16;
  const int r16 = lane & 15, g = lane >> 4;
  const size_t tokbase = (size_t)b * SS;
  const size_t hoff = (size_t)h * DQK;

  // Q fragments (B-operand): col = q = r16, k = kc*32 + g*8 + e
  short8 qf[2];
#pragma unroll
  for (int kc = 0; kc < 2; ++kc)
    qf[kc] = *(const short8*)(Q + (tokbase + q0 + r16) * DD + hoff + kc * 32 + g * 8);

  f32x4 o[4];
#pragma unroll
  for (int dt = 0; dt < 4; ++dt) o[dt] = (f32x4){0.f, 0.f, 0.f, 0.f};
  float rm = -INFINITY, rl = 0.f;
  const int lim = q0 + 15;                   // max valid key for this wave

  for (int j0 = 0; j0 <= lim; j0 += 64) {
    // --- QK^T: A = K tile (rows = keys), B = Q. S[key][q] ---
    float sv[4][4];
#pragma unroll
    for (int t2 = 0; t2 < 4; ++t2) {
      const int kbase = j0 + t2 * 16;
      if (kbase <= lim) {  // wave-uniform
        const ushort* kp = K + (tokbase + kbase + r16) * DD + hoff + g * 8;
        const short8 kf0 = *(const short8*)(kp);
        const short8 kf1 = *(const short8*)(kp + 32);
        f32x4 s = mfma16(kf0, qf[0], (f32x4){0.f, 0.f, 0.f, 0.f});
        s = mfma16(kf1, qf[1], s);
#pragma unroll
        for (int r = 0; r < 4; ++r)
          sv[t2][r] = (kbase + g * 4 + r <= q0 + r16) ? s[r] * 0.125f : -INFINITY;
      } else {
#pragma unroll
        for (int r = 0; r < 4; ++r) sv[t2][r] = -INFINITY;
      }
    }

    // --- online softmax for q = r16: in-lane tree + 2 shuffles ---
    float mx01 = fmaxf(fmaxf(sv[0][0], sv[0][1]), fmaxf(sv[0][2], sv[0][3]));
    float mx23 = fmaxf(fmaxf(sv[1][0], sv[1][1]), fmaxf(sv[1][2], sv[1][3]));
    float mx45 = fmaxf(fmaxf(sv[2][0], sv[2][1]), fmaxf(sv[2][2], sv[2][3]));
    float mx67 = fmaxf(fmaxf(sv[3][0], sv[3][1]), fmaxf(sv[3][2], sv[3][3]));
    float mx = fmaxf(fmaxf(mx01, mx23), fmaxf(mx45, mx67));
    mx = fmaxf(mx, __shfl_xor(mx, 16));
    mx = fmaxf(mx, __shfl_xor(mx, 32));
    const float mn = fmaxf(rm, mx);
    const float sc = __expf(rm - mn);
    float p[4][4];
    float ps = 0.f;
#pragma unroll
    for (int t2 = 0; t2 < 4; ++t2) {
      float s0 = __expf(sv[t2][0] - mn);
      float s1 = __expf(sv[t2][1] - mn);
      float s2 = __expf(sv[t2][2] - mn);
      float s3 = __expf(sv[t2][3] - mn);
      p[t2][0] = s0; p[t2][1] = s1; p[t2][2] = s2; p[t2][3] = s3;
      ps += (s0 + s1) + (s2 + s3);
    }
    ps += __shfl_xor(ps, 16);
    ps += __shfl_xor(ps, 32);
    rl = rl * sc + ps;
    rm = mn;
#pragma unroll
    for (int dt = 0; dt < 4; ++dt) o[dt] *= sc;

    // --- P -> bf16 -> LDS: p_lds[q][key], key = t2*16 + g*4 + r ---
#pragma unroll
    for (int t2 = 0; t2 < 4; ++t2) {
      ushort4 pk;
      pk.x = f2bf(p[t2][0]);
      pk.y = f2bf(p[t2][1]);
      pk.z = f2bf(p[t2][2]);
      pk.w = f2bf(p[t2][3]);
      *(ushort4*)&p_lds[ww][r16][t2 * 16 + g * 4] = pk;
    }

    // --- PV: A = Vt (rows = dq), B = P (cols = q). O[dq][q] ---
#pragma unroll
    for (int kc = 0; kc < 2; ++kc) {
      if (j0 + kc * 32 <= lim) {  // wave-uniform
        const short8 pb = *(const short8*)&p_lds[ww][r16][kc * 32 + g * 8];
#pragma unroll
        for (int dt = 0; dt < 4; ++dt) {
          const short8 vf = *(const short8*)(Vt + ((size_t)bh * DQK + dt * 16 + r16) * SS +
                                             j0 + kc * 32 + g * 8);
          o[dt] = mfma16(vf, pb, o[dt]);
        }
      }
    }
  }

  // --- epilogue: O[token q0+r16][h*64 + dt*16 + g*4 + r], lane-scalar 1/rl ---
  const float inv = 1.0f / rl;
#pragma unroll
  for (int dt = 0; dt < 4; ++dt) {
    ushort4 st;
    st.x = f2bf(o[dt][0] * inv);
    st.y = f2bf(o[dt][1] * inv);
    st.z = f2bf(o[dt][2] * inv);
    st.w = f2bf(o[dt][3] * inv);
    *(ushort4*)(O + (tokbase + q0 + r16) * DD + hoff + dt * 16 + g * 4) = st;
  }
}

// ---------------------------------------------------------------------------
// Launch: wtrans -> LN -> 3x GEMM (Q,K -> bf16; V -> Vt) -> attn -> O-GEMM.
// ws: xn 8MB | q 8MB | k 8MB | vt 8MB | att 8MB | wt 16MB  (48MB)
// ---------------------------------------------------------------------------
extern "C" void kernel_launch(void* const* d_in, const int* in_sizes, int n_in,
                              void* d_out, int out_size, void* d_ws, size_t ws_size,
                              hipStream_t stream) {
  const float* x    = (const float*)d_in[0];
  const float* ln_g = (const float*)d_in[1];
  const float* ln_b = (const float*)d_in[2];
  const float* Wq   = (const float*)d_in[3];
  const float* bq   = (const float*)d_in[4];
  const float* Wk   = (const float*)d_in[5];
  const float* bk   = (const float*)d_in[6];
  const float* Wv   = (const float*)d_in[7];
  const float* bv   = (const float*)d_in[8];
  const float* Wo   = (const float*)d_in[9];
  const float* bo   = (const float*)d_in[10];
  float* out = (float*)d_out;

  ushort* ws  = (ushort*)d_ws;
  ushort* xn  = ws;
  ushort* qb  = xn + NE;
  ushort* kb  = qb + NE;
  ushort* vt  = kb + NE;
  ushort* ab  = vt + NE;
  ushort* wt  = ab + NE;               // 4 x [1024][1024] bf16
  ushort* wqt = wt;
  ushort* wkt = wt + (size_t)DD * DD;
  ushort* wvt = wt + (size_t)2 * DD * DD;
  ushort* wot = wt + (size_t)3 * DD * DD;

  wtrans<<<dim3(16, 16, 4), 256, 0, stream>>>(Wq, Wk, Wv, Wo, wt);
  ln_fwd<<<NROWS, 256, 0, stream>>>(x, ln_g, ln_b, xn);

  dim3 gg(NROWS / 128, DD / 128);  // (32, 8)
  gemm_mfma<0><<<gg, 256, 0, stream>>>(xn, wqt, bq, nullptr, qb, nullptr);
  gemm_mfma<0><<<gg, 256, 0, stream>>>(xn, wkt, bk, nullptr, kb, nullptr);
  gemm_mfma<1><<<gg, 256, 0, stream>>>(xn, wvt, bv, nullptr, vt, nullptr);

  attn_mfma<<<BB * HH * (SS / 16) / 4, 256, 0, stream>>>(qb, kb, vt, ab);

  gemm_mfma<2><<<gg, 256, 0, stream>>>(ab, wot, bo, x, nullptr, out);
}

// Round 4
// 156.483 us; speedup vs baseline: 10.3140x; 2.1330x over previous
//
#include <hip/hip_runtime.h>
#include <math.h>

// Problem constants: B=2, S=2048, D=1024, H=16, DQ=64
#define BB 2
#define SS 2048
#define DD 1024
#define HH 16
#define DQK 64
#define NROWS (BB * SS)
#define NE ((size_t)BB * SS * DD)   // 4,194,304

using short8 = __attribute__((ext_vector_type(8))) short;
using f32x4  = __attribute__((ext_vector_type(4))) float;

__device__ __forceinline__ ushort f2bf(float f) {
  union { float f; unsigned u; } c; c.f = f;
  return (ushort)((c.u + 0x7fffu + ((c.u >> 16) & 1u)) >> 16);
}

__device__ __forceinline__ f32x4 mfma16(short8 a, short8 b, f32x4 c) {
  return __builtin_amdgcn_mfma_f32_16x16x32_bf16(a, b, c, 0, 0, 0);
}

typedef __attribute__((address_space(1))) const unsigned gas_u32;
typedef __attribute__((address_space(3))) unsigned las_u32;
__device__ __forceinline__ void gload_lds16(const void* g, void* l) {
  __builtin_amdgcn_global_load_lds((gas_u32*)g, (las_u32*)l, 16, 0, 0);
}

// ---------------------------------------------------------------------------
// LayerNorm -> bf16. One block per row.
// ---------------------------------------------------------------------------
__global__ __launch_bounds__(256) void ln_fwd(const float* __restrict__ x,
                                              const float* __restrict__ g,
                                              const float* __restrict__ bta,
                                              ushort* __restrict__ xn) {
  const int row = blockIdx.x;
  const int t = threadIdx.x;
  float4 v = ((const float4*)(x + (size_t)row * DD))[t];
  float s  = v.x + v.y + v.z + v.w;
  float ss = v.x * v.x + v.y * v.y + v.z * v.z + v.w * v.w;
#pragma unroll
  for (int off = 32; off > 0; off >>= 1) {
    s  += __shfl_xor(s, off);
    ss += __shfl_xor(ss, off);
  }
  __shared__ float red[8];
  const int wid = t >> 6, lane = t & 63;
  if (lane == 0) { red[wid] = s; red[4 + wid] = ss; }
  __syncthreads();
  const float stot  = red[0] + red[1] + red[2] + red[3];
  const float sstot = red[4] + red[5] + red[6] + red[7];
  const float mu  = stot * (1.0f / DD);
  const float var = sstot * (1.0f / DD) - mu * mu;
  const float inv = rsqrtf(var + 1e-5f);
  const float4 g4 = ((const float4*)g)[t];
  const float4 b4 = ((const float4*)bta)[t];
  ushort4 o;
  o.x = f2bf((v.x - mu) * inv * g4.x + b4.x);
  o.y = f2bf((v.y - mu) * inv * g4.y + b4.y);
  o.z = f2bf((v.z - mu) * inv * g4.z + b4.z);
  o.w = f2bf((v.w - mu) * inv * g4.w + b4.w);
  ((ushort4*)(xn + (size_t)row * DD))[t] = o;
}

// ---------------------------------------------------------------------------
// Transpose + bf16-cast the 4 weight matrices: W[K][N] fp32 -> Wt[N][K] bf16.
// ---------------------------------------------------------------------------
__global__ __launch_bounds__(256) void wtrans(const float* __restrict__ Wq,
                                              const float* __restrict__ Wk,
                                              const float* __restrict__ Wv,
                                              const float* __restrict__ Wo,
                                              ushort* __restrict__ wt) {
  const int z = blockIdx.z;
  const float* W = (z == 0) ? Wq : (z == 1) ? Wk : (z == 2) ? Wv : Wo;
  ushort* dst = wt + (size_t)z * DD * DD;
  __shared__ float tile[64][65];
  const int t = threadIdx.x;
  const int k0 = blockIdx.x * 64, n0 = blockIdx.y * 64;
  const int tr = t >> 4, tc = (t & 15) * 4;
#pragma unroll
  for (int rr = 0; rr < 64; rr += 16) {
    float4 v = *(const float4*)(W + (size_t)(k0 + rr + tr) * DD + n0 + tc);
    tile[rr + tr][tc + 0] = v.x;
    tile[rr + tr][tc + 1] = v.y;
    tile[rr + tr][tc + 2] = v.z;
    tile[rr + tr][tc + 3] = v.w;
  }
  __syncthreads();
#pragma unroll
  for (int rr = 0; rr < 64; rr += 16) {
    const int n = rr + tr;
    ushort4 o;
    o.x = f2bf(tile[tc + 0][n]);
    o.y = f2bf(tile[tc + 1][n]);
    o.z = f2bf(tile[tc + 2][n]);
    o.w = f2bf(tile[tc + 3][n]);
    *(ushort4*)(dst + (size_t)(n0 + n) * DD + k0 + tc) = o;
  }
}

// ---------------------------------------------------------------------------
// bf16 MFMA GEMM, 128x128 tile, 4 waves, BK=32, reg-staged LDS with XOR
// swizzle (frag reads were 8-way bank conflicts unswizzled).
// MODE 0: bf16 out. MODE 1: bf16 out transposed per-head (Vt). MODE 2: fp32+res.
// ---------------------------------------------------------------------------
template <int MODE>
__global__ __launch_bounds__(256) void gemm_mfma(
    const ushort* __restrict__ A, const ushort* __restrict__ Bt,
    const float* __restrict__ bias, const float* __restrict__ resid,
    ushort* __restrict__ outb, float* __restrict__ outf) {
  __shared__ ushort As[128][32];  // 64B rows, XOR-swizzled in 16B units
  __shared__ ushort Bs[128][32];
  const int t = threadIdx.x;
  const int lane = t & 63;
  const int w = t >> 6, wr = w >> 1, wc = w & 1;
  const int r16 = lane & 15, g = lane >> 4;
  const int row0 = blockIdx.x * 128, col0 = blockIdx.y * 128;

  f32x4 acc[4][4];
#pragma unroll
  for (int m = 0; m < 4; ++m)
#pragma unroll
    for (int n = 0; n < 4; ++n) acc[m][n] = (f32x4){0.f, 0.f, 0.f, 0.f};

  const int srow = t >> 2, skb = (t & 3) * 16;          // store row / byte-col
  const int ssw = (srow & 3) << 4;
  const int fsw = (r16 & 3) << 4;                        // frag-read swizzle
  const ushort* Ap = A + (size_t)(row0 + srow) * DD + (t & 3) * 8;
  const ushort* Bp = Bt + (size_t)(col0 + srow) * DD + (t & 3) * 8;

  for (int k0 = 0; k0 < DD; k0 += 32) {
    short8 a0 = *(const short8*)(Ap + k0);
    short8 a1 = *(const short8*)(Ap + (size_t)64 * DD + k0);
    short8 b0 = *(const short8*)(Bp + k0);
    short8 b1 = *(const short8*)(Bp + (size_t)64 * DD + k0);
    __syncthreads();
    *(short8*)((char*)&As[0][0] + srow * 64 + (skb ^ ssw)) = a0;
    *(short8*)((char*)&As[0][0] + (srow + 64) * 64 + (skb ^ ssw)) = a1;
    *(short8*)((char*)&Bs[0][0] + srow * 64 + (skb ^ ssw)) = b0;
    *(short8*)((char*)&Bs[0][0] + (srow + 64) * 64 + (skb ^ ssw)) = b1;
    __syncthreads();
    short8 af[4], bf[4];
#pragma unroll
    for (int m = 0; m < 4; ++m)
      af[m] = *(const short8*)((const char*)&As[0][0] +
                               (wr * 64 + m * 16 + r16) * 64 + ((g * 16) ^ fsw));
#pragma unroll
    for (int n = 0; n < 4; ++n)
      bf[n] = *(const short8*)((const char*)&Bs[0][0] +
                               (wc * 64 + n * 16 + r16) * 64 + ((g * 16) ^ fsw));
#pragma unroll
    for (int m = 0; m < 4; ++m)
#pragma unroll
      for (int n = 0; n < 4; ++n) acc[m][n] = mfma16(af[m], bf[n], acc[m][n]);
  }

#pragma unroll
  for (int n = 0; n < 4; ++n) {
    const int c = col0 + wc * 64 + n * 16 + r16;
    const float bc = bias[c];
#pragma unroll
    for (int m = 0; m < 4; ++m) {
      const int rbase = row0 + wr * 64 + m * 16 + g * 4;
      if (MODE == 0) {
#pragma unroll
        for (int e = 0; e < 4; ++e)
          outb[(size_t)(rbase + e) * DD + c] = f2bf(acc[m][n][e] + bc);
      } else if (MODE == 1) {
        ushort4 st;
        st.x = f2bf(acc[m][n][0] + bc);
        st.y = f2bf(acc[m][n][1] + bc);
        st.z = f2bf(acc[m][n][2] + bc);
        st.w = f2bf(acc[m][n][3] + bc);
        const size_t vrow = (size_t)((rbase >> 11) * HH + (c >> 6)) * DQK + (c & 63);
        *(ushort4*)(outb + vrow * SS + (rbase & 2047)) = st;
      } else {
#pragma unroll
        for (int e = 0; e < 4; ++e) {
          const size_t idx = (size_t)(rbase + e) * DD + c;
          outf[idx] = acc[m][n][e] + bc + resid[idx];
        }
      }
    }
  }
}

// ---------------------------------------------------------------------------
// MFMA flash attention (causal), block-cooperative. 4 waves/block share one
// (b,h) and a 64-row q-block (wave ww owns rows qb*64+ww*16 ..+15). K/V tiles
// (64 keys) staged ONCE per block into double-buffered LDS via global_load_lds
// w=16, XOR-swizzled via pre-swizzled global source. 2-phase pipeline: one
// vmcnt(0)+barrier per tile. Only the last tile needs causal masking.
// ---------------------------------------------------------------------------
__global__ __launch_bounds__(256) void attn_mfma(const ushort* __restrict__ Q,
                                                 const ushort* __restrict__ K,
                                                 const ushort* __restrict__ Vt,
                                                 ushort* __restrict__ O) {
  __shared__ ushort Ks[2][64][64];  // [buf][key][d]  128B rows, swizzled
  __shared__ ushort Vs[2][64][64];  // [buf][dq][key] 128B rows, swizzled
  __shared__ ushort Ps[4][16][64];  // [wave][q][key] 128B rows, swizzled

  const int t = threadIdx.x, lane = t & 63, ww = t >> 6;
  const int r16 = lane & 15, g = lane >> 4;

  // work mapping: xcd-major, 4 heads per XCD, heavy q-blocks first
  const int bid = blockIdx.x;
  const int xcd = bid & 7, idx = bid >> 3;       // idx 0..127
  const int bh = xcd * 4 + (idx & 3);            // 0..31
  const int qb = 31 - (idx >> 2);                // heavy first
  const int b = bh >> 4, h = bh & 15;
  const int q0 = qb * 64 + ww * 16;
  const int nt = qb + 1;
  const size_t tokbase = (size_t)b * SS;
  const size_t hoff = (size_t)h * DQK;

  // staging coords: thread t covers LDS bytes [t*16, t*16+16) of each 4KB half
  const int srow = t >> 3;                       // 0..31
  const int scol = (t & 7) * 16;                 // 0..112
  const char* Kb = (const char*)(K + tokbase * DD + hoff);
  const char* Vb = (const char*)(Vt + (size_t)bh * DQK * SS);
  const int sw = (r16 & 7) << 4;                 // frag-read swizzle

  // Q fragments (B-operand): col=q=r16, k = kc*32 + g*8 + e
  short8 qf[2];
#pragma unroll
  for (int kc = 0; kc < 2; ++kc)
    qf[kc] = *(const short8*)(Q + (tokbase + q0 + r16) * DD + hoff + kc * 32 + g * 8);

  f32x4 o[4];
#pragma unroll
  for (int dt = 0; dt < 4; ++dt) o[dt] = (f32x4){0.f, 0.f, 0.f, 0.f};
  float rm = -INFINITY, rl = 0.f;
  const int thr = q0 + r16 - g * 4;              // causal: t*64+t2*16+r <= thr

#define STAGE(buf, j0)                                                        \
  {                                                                           \
    _Pragma("unroll")                                                         \
    for (int i = 0; i < 2; ++i) {                                             \
      const int R = i * 32 + srow;                                            \
      const int Cs = scol ^ ((R & 7) << 4);                                   \
      gload_lds16(Kb + ((size_t)((j0) + R) * DD) * 2 + Cs,                    \
                  (char*)&Ks[buf][0][0] + i * 4096 + ww * 1024);              \
      gload_lds16(Vb + ((size_t)R * SS + (j0)) * 2 + Cs,                      \
                  (char*)&Vs[buf][0][0] + i * 4096 + ww * 1024);              \
    }                                                                         \
  }

  STAGE(0, 0);
  int cur = 0;
  for (int tt = 0; tt < nt; ++tt) {
    asm volatile("s_waitcnt vmcnt(0)" ::: "memory");
    __syncthreads();                             // buf[cur] staged by all waves
    if (tt + 1 < nt) STAGE(cur ^ 1, (tt + 1) * 64);

    const char* Kc = (const char*)&Ks[cur][0][0];
    const char* Vc = (const char*)&Vs[cur][0][0];

    // --- QK^T: A = K rows (keys), B = Q. S[key][q], q = r16 lane-resident ---
    f32x4 s4[4];
#pragma unroll
    for (int t2 = 0; t2 < 4; ++t2) {
      const int rb = (t2 * 16 + r16) * 128;
      const short8 k0 = *(const short8*)(Kc + rb + ((g * 16) ^ sw));
      const short8 k1 = *(const short8*)(Kc + rb + ((64 + g * 16) ^ sw));
      f32x4 s = mfma16(k0, qf[0], (f32x4){0.f, 0.f, 0.f, 0.f});
      s4[t2] = mfma16(k1, qf[1], s);
    }
    float sv[4][4];
    const bool last = (tt == nt - 1);            // block-uniform
#pragma unroll
    for (int t2 = 0; t2 < 4; ++t2)
#pragma unroll
      for (int r = 0; r < 4; ++r) {
        float xv = s4[t2][r] * 0.125f;           // 1/sqrt(64)
        if (last) xv = (tt * 64 + t2 * 16 + r <= thr) ? xv : -INFINITY;
        sv[t2][r] = xv;
      }

    // --- online softmax: in-lane tree + 2 shuffles ---
    float mx = fmaxf(fmaxf(fmaxf(sv[0][0], sv[0][1]), fmaxf(sv[0][2], sv[0][3])),
                     fmaxf(fmaxf(sv[1][0], sv[1][1]), fmaxf(sv[1][2], sv[1][3])));
    mx = fmaxf(mx, fmaxf(fmaxf(fmaxf(sv[2][0], sv[2][1]), fmaxf(sv[2][2], sv[2][3])),
                         fmaxf(fmaxf(sv[3][0], sv[3][1]), fmaxf(sv[3][2], sv[3][3]))));
    mx = fmaxf(mx, __shfl_xor(mx, 16));
    mx = fmaxf(mx, __shfl_xor(mx, 32));
    const float mn = fmaxf(rm, mx);
    const float sc = __expf(rm - mn);
    float ps = 0.f;
#pragma unroll
    for (int t2 = 0; t2 < 4; ++t2) {
      const float p0 = __expf(sv[t2][0] - mn);
      const float p1 = __expf(sv[t2][1] - mn);
      const float p2 = __expf(sv[t2][2] - mn);
      const float p3 = __expf(sv[t2][3] - mn);
      ps += (p0 + p1) + (p2 + p3);
      ushort4 pk;
      pk.x = f2bf(p0); pk.y = f2bf(p1); pk.z = f2bf(p2); pk.w = f2bf(p3);
      *(ushort4*)((char*)&Ps[ww][0][0] + r16 * 128 + ((t2 * 32 + g * 8) ^ sw)) = pk;
    }
    ps += __shfl_xor(ps, 16);
    ps += __shfl_xor(ps, 32);
    rl = rl * sc + ps;
    rm = mn;
#pragma unroll
    for (int dt = 0; dt < 4; ++dt) o[dt] *= sc;

    // --- PV: A = V rows (dq), B = P. O[dq][q] ---
#pragma unroll
    for (int kc = 0; kc < 2; ++kc) {
      const short8 pb = *(const short8*)((const char*)&Ps[ww][0][0] + r16 * 128 +
                                         ((kc * 64 + g * 16) ^ sw));
#pragma unroll
      for (int dt = 0; dt < 4; ++dt) {
        const short8 vf = *(const short8*)(Vc + (dt * 16 + r16) * 128 +
                                           ((kc * 64 + g * 16) ^ sw));
        o[dt] = mfma16(vf, pb, o[dt]);
      }
    }
    cur ^= 1;
  }
#undef STAGE

  // --- epilogue: lane (r16,g) holds O[dq=dt*16+g*4+r][q=r16] ---
  const float inv = 1.0f / rl;
#pragma unroll
  for (int dt = 0; dt < 4; ++dt) {
    ushort4 st;
    st.x = f2bf(o[dt][0] * inv);
    st.y = f2bf(o[dt][1] * inv);
    st.z = f2bf(o[dt][2] * inv);
    st.w = f2bf(o[dt][3] * inv);
    *(ushort4*)(O + (tokbase + q0 + r16) * DD + hoff + dt * 16 + g * 4) = st;
  }
}

// ---------------------------------------------------------------------------
// Launch: wtrans -> LN -> 3x GEMM (Q,K -> bf16; V -> Vt) -> attn -> O-GEMM.
// ws: xn 8MB | q 8MB | k 8MB | vt 8MB | att 8MB | wt 16MB  (56MB)
// ---------------------------------------------------------------------------
extern "C" void kernel_launch(void* const* d_in, const int* in_sizes, int n_in,
                              void* d_out, int out_size, void* d_ws, size_t ws_size,
                              hipStream_t stream) {
  const float* x    = (const float*)d_in[0];
  const float* ln_g = (const float*)d_in[1];
  const float* ln_b = (const float*)d_in[2];
  const float* Wq   = (const float*)d_in[3];
  const float* bq   = (const float*)d_in[4];
  const float* Wk   = (const float*)d_in[5];
  const float* bk   = (const float*)d_in[6];
  const float* Wv   = (const float*)d_in[7];
  const float* bv   = (const float*)d_in[8];
  const float* Wo   = (const float*)d_in[9];
  const float* bo   = (const float*)d_in[10];
  float* out = (float*)d_out;

  ushort* ws  = (ushort*)d_ws;
  ushort* xn  = ws;
  ushort* qb  = xn + NE;
  ushort* kb  = qb + NE;
  ushort* vt  = kb + NE;
  ushort* ab  = vt + NE;
  ushort* wt  = ab + NE;               // 4 x [1024][1024] bf16
  ushort* wqt = wt;
  ushort* wkt = wt + (size_t)DD * DD;
  ushort* wvt = wt + (size_t)2 * DD * DD;
  ushort* wot = wt + (size_t)3 * DD * DD;

  wtrans<<<dim3(16, 16, 4), 256, 0, stream>>>(Wq, Wk, Wv, Wo, wt);
  ln_fwd<<<NROWS, 256, 0, stream>>>(x, ln_g, ln_b, xn);

  dim3 gg(NROWS / 128, DD / 128);  // (32, 8)
  gemm_mfma<0><<<gg, 256, 0, stream>>>(xn, wqt, bq, nullptr, qb, nullptr);
  gemm_mfma<0><<<gg, 256, 0, stream>>>(xn, wkt, bk, nullptr, kb, nullptr);
  gemm_mfma<1><<<gg, 256, 0, stream>>>(xn, wvt, bv, nullptr, vt, nullptr);

  attn_mfma<<<BB * HH * (SS / 64), 256, 0, stream>>>(qb, kb, vt, ab);

  gemm_mfma<2><<<gg, 256, 0, stream>>>(ab, wot, bo, x, nullptr, out);
}

// Round 5
// 121.219 us; speedup vs baseline: 13.3145x; 1.2909x over previous
//
#include <hip/hip_runtime.h>
#include <math.h>

// Problem constants: B=2, S=2048, D=1024, H=16, DQ=64
#define BB 2
#define SS 2048
#define DD 1024
#define HH 16
#define DQK 64
#define NROWS (BB * SS)
#define NE ((size_t)BB * SS * DD)   // 4,194,304

using short8 = __attribute__((ext_vector_type(8))) short;
using f32x4  = __attribute__((ext_vector_type(4))) float;

__device__ __forceinline__ ushort f2bf(float f) {
  union { float f; unsigned u; } c; c.f = f;
  return (ushort)((c.u + 0x7fffu + ((c.u >> 16) & 1u)) >> 16);
}

__device__ __forceinline__ unsigned cvt_pk_bf16(float lo, float hi) {
  unsigned r;
  asm("v_cvt_pk_bf16_f32 %0, %1, %2" : "=v"(r) : "v"(lo), "v"(hi));
  return r;
}

__device__ __forceinline__ f32x4 mfma16(short8 a, short8 b, f32x4 c) {
  return __builtin_amdgcn_mfma_f32_16x16x32_bf16(a, b, c, 0, 0, 0);
}

typedef __attribute__((address_space(1))) const unsigned gas_u32;
typedef __attribute__((address_space(3))) unsigned las_u32;
__device__ __forceinline__ void gload_lds16(const void* g, void* l) {
  __builtin_amdgcn_global_load_lds((gas_u32*)g, (las_u32*)l, 16, 0, 0);
}

// ---------------------------------------------------------------------------
// LayerNorm -> bf16. One block per row.
// ---------------------------------------------------------------------------
__global__ __launch_bounds__(256) void ln_fwd(const float* __restrict__ x,
                                              const float* __restrict__ g,
                                              const float* __restrict__ bta,
                                              ushort* __restrict__ xn) {
  const int row = blockIdx.x;
  const int t = threadIdx.x;
  float4 v = ((const float4*)(x + (size_t)row * DD))[t];
  float s  = v.x + v.y + v.z + v.w;
  float ss = v.x * v.x + v.y * v.y + v.z * v.z + v.w * v.w;
#pragma unroll
  for (int off = 32; off > 0; off >>= 1) {
    s  += __shfl_xor(s, off);
    ss += __shfl_xor(ss, off);
  }
  __shared__ float red[8];
  const int wid = t >> 6, lane = t & 63;
  if (lane == 0) { red[wid] = s; red[4 + wid] = ss; }
  __syncthreads();
  const float stot  = red[0] + red[1] + red[2] + red[3];
  const float sstot = red[4] + red[5] + red[6] + red[7];
  const float mu  = stot * (1.0f / DD);
  const float var = sstot * (1.0f / DD) - mu * mu;
  const float inv = rsqrtf(var + 1e-5f);
  const float4 g4 = ((const float4*)g)[t];
  const float4 b4 = ((const float4*)bta)[t];
  ushort4 o;
  o.x = f2bf((v.x - mu) * inv * g4.x + b4.x);
  o.y = f2bf((v.y - mu) * inv * g4.y + b4.y);
  o.z = f2bf((v.z - mu) * inv * g4.z + b4.z);
  o.w = f2bf((v.w - mu) * inv * g4.w + b4.w);
  ((ushort4*)(xn + (size_t)row * DD))[t] = o;
}

// ---------------------------------------------------------------------------
// Transpose + bf16-cast the 4 weight matrices: W[K][N] fp32 -> Wt[N][K] bf16.
// ---------------------------------------------------------------------------
__global__ __launch_bounds__(256) void wtrans(const float* __restrict__ Wq,
                                              const float* __restrict__ Wk,
                                              const float* __restrict__ Wv,
                                              const float* __restrict__ Wo,
                                              ushort* __restrict__ wt) {
  const int z = blockIdx.z;
  const float* W = (z == 0) ? Wq : (z == 1) ? Wk : (z == 2) ? Wv : Wo;
  ushort* dst = wt + (size_t)z * DD * DD;
  __shared__ float tile[64][65];
  const int t = threadIdx.x;
  const int k0 = blockIdx.x * 64, n0 = blockIdx.y * 64;
  const int tr = t >> 4, tc = (t & 15) * 4;
#pragma unroll
  for (int rr = 0; rr < 64; rr += 16) {
    float4 v = *(const float4*)(W + (size_t)(k0 + rr + tr) * DD + n0 + tc);
    tile[rr + tr][tc + 0] = v.x;
    tile[rr + tr][tc + 1] = v.y;
    tile[rr + tr][tc + 2] = v.z;
    tile[rr + tr][tc + 3] = v.w;
  }
  __syncthreads();
#pragma unroll
  for (int rr = 0; rr < 64; rr += 16) {
    const int n = rr + tr;
    ushort4 o;
    o.x = f2bf(tile[tc + 0][n]);
    o.y = f2bf(tile[tc + 1][n]);
    o.z = f2bf(tile[tc + 2][n]);
    o.w = f2bf(tile[tc + 3][n]);
    *(ushort4*)(dst + (size_t)(n0 + n) * DD + k0 + tc) = o;
  }
}

// ---------------------------------------------------------------------------
// GEMM core pieces. 128x128 tile, 4 waves, BK=32, global_load_lds staging
// (linear LDS dest, pre-swizzled global source; read-side XOR (r16&3)<<4),
// double-buffered, one vmcnt(0)+barrier per k-step.
// ---------------------------------------------------------------------------
#define GEMM_CORE(Ag, Bg)                                                     \
  f32x4 acc[4][4];                                                            \
  _Pragma("unroll")                                                           \
  for (int m = 0; m < 4; ++m)                                                 \
    _Pragma("unroll")                                                         \
    for (int n = 0; n < 4; ++n) acc[m][n] = (f32x4){0.f, 0.f, 0.f, 0.f};     \
  const int cs = ((t & 3) * 16) ^ (((t >> 2) & 3) * 16);                      \
  const int fsw = (r16 & 3) * 16;                                             \
  {                                                                           \
    GSTAGE(Ag, Bg, 0, 0);                                                     \
    int cur = 0;                                                              \
    for (int k0 = 0; k0 < DD; k0 += 32) {                                     \
      asm volatile("s_waitcnt vmcnt(0)" ::: "memory");                        \
      __syncthreads();                                                        \
      if (k0 + 32 < DD) GSTAGE(Ag, Bg, cur ^ 1, k0 + 32);                     \
      const char* Ac = (const char*)&As[cur][0][0];                           \
      const char* Bc = (const char*)&Bs[cur][0][0];                           \
      short8 af[4], bf[4];                                                    \
      _Pragma("unroll")                                                       \
      for (int m = 0; m < 4; ++m)                                             \
        af[m] = *(const short8*)(Ac + (wr * 64 + m * 16 + r16) * 64 +         \
                                 ((g * 16) ^ fsw));                           \
      _Pragma("unroll")                                                       \
      for (int n = 0; n < 4; ++n)                                             \
        bf[n] = *(const short8*)(Bc + (wc * 64 + n * 16 + r16) * 64 +         \
                                 ((g * 16) ^ fsw));                           \
      _Pragma("unroll")                                                       \
      for (int m = 0; m < 4; ++m)                                             \
        _Pragma("unroll")                                                     \
        for (int n = 0; n < 4; ++n) acc[m][n] = mfma16(af[m], bf[n], acc[m][n]); \
      cur ^= 1;                                                               \
    }                                                                         \
  }

#define GSTAGE(Ag, Bg, buf, k0)                                               \
  {                                                                           \
    _Pragma("unroll")                                                         \
    for (int i = 0; i < 2; ++i) {                                             \
      gload_lds16(Ag + (size_t)(row0 + i * 64 + (t >> 2)) * (DD * 2) +        \
                      (k0) * 2 + cs,                                          \
                  (char*)&As[buf][0][0] + i * 4096 + t * 16);                 \
      gload_lds16(Bg + (size_t)(col0 + i * 64 + (t >> 2)) * (DD * 2) +        \
                      (k0) * 2 + cs,                                          \
                  (char*)&Bs[buf][0][0] + i * 4096 + t * 16);                 \
    }                                                                         \
  }

// Fused QKV projection: A[4096][1024] @ {Wq,Wk,Wv}t -> qb, kb (bf16 [M][N]),
// vt (bf16 per-head transposed). grid (32, 24): y>>3 = matrix, y&7 = col blk.
__global__ __launch_bounds__(256) void gemm_qkv(
    const ushort* __restrict__ A, const ushort* __restrict__ wt,
    const float* __restrict__ bq, const float* __restrict__ bk,
    const float* __restrict__ bv, ushort* __restrict__ qb,
    ushort* __restrict__ kb, ushort* __restrict__ vt) {
  __shared__ ushort As[2][128][32];
  __shared__ ushort Bs[2][128][32];
  const int t = threadIdx.x;
  const int lane = t & 63;
  const int w = t >> 6, wr = w >> 1, wc = w & 1;
  const int r16 = lane & 15, g = lane >> 4;
  const int row0 = blockIdx.x * 128;
  const int mat = blockIdx.y >> 3;
  const int col0 = (blockIdx.y & 7) * 128;
  const char* Ag = (const char*)A;
  const char* Bg = (const char*)(wt + (size_t)mat * DD * DD);
  const float* bias = (mat == 0) ? bq : (mat == 1) ? bk : bv;

  GEMM_CORE(Ag, Bg)

#pragma unroll
  for (int n = 0; n < 4; ++n) {
    const int c = col0 + wc * 64 + n * 16 + r16;
    const float bc = bias[c];
#pragma unroll
    for (int m = 0; m < 4; ++m) {
      const int rbase = row0 + wr * 64 + m * 16 + g * 4;
      if (mat < 2) {
        ushort* outb = (mat == 0) ? qb : kb;
#pragma unroll
        for (int e = 0; e < 4; ++e)
          outb[(size_t)(rbase + e) * DD + c] = f2bf(acc[m][n][e] + bc);
      } else {
        uint2 st;
        st.x = cvt_pk_bf16(acc[m][n][0] + bc, acc[m][n][1] + bc);
        st.y = cvt_pk_bf16(acc[m][n][2] + bc, acc[m][n][3] + bc);
        const size_t vrow = (size_t)((rbase >> 11) * HH + (c >> 6)) * DQK + (c & 63);
        *(uint2*)(vt + vrow * SS + (rbase & 2047)) = st;
      }
    }
  }
}

// Output projection: att @ Wo + bo + x -> fp32 out.
__global__ __launch_bounds__(256) void gemm_o(
    const ushort* __restrict__ A, const ushort* __restrict__ Bt,
    const float* __restrict__ bias, const float* __restrict__ resid,
    float* __restrict__ outf) {
  __shared__ ushort As[2][128][32];
  __shared__ ushort Bs[2][128][32];
  const int t = threadIdx.x;
  const int lane = t & 63;
  const int w = t >> 6, wr = w >> 1, wc = w & 1;
  const int r16 = lane & 15, g = lane >> 4;
  const int row0 = blockIdx.x * 128;
  const int col0 = blockIdx.y * 128;
  const char* Ag = (const char*)A;
  const char* Bg = (const char*)Bt;

  GEMM_CORE(Ag, Bg)

#pragma unroll
  for (int n = 0; n < 4; ++n) {
    const int c = col0 + wc * 64 + n * 16 + r16;
    const float bc = bias[c];
#pragma unroll
    for (int m = 0; m < 4; ++m) {
      const int rbase = row0 + wr * 64 + m * 16 + g * 4;
#pragma unroll
      for (int e = 0; e < 4; ++e) {
        const size_t idx = (size_t)(rbase + e) * DD + c;
        outf[idx] = acc[m][n][e] + bc + resid[idx];
      }
    }
  }
}

// ---------------------------------------------------------------------------
// MFMA flash attention (causal), block-cooperative, balanced. Each block
// handles q-block pair (p, 31-p) of one (b,h) -> exactly 33 tile-iterations
// per block (512 blocks, uniform work). Per 64-key tile: K/V staged once via
// global_load_lds (swizzled source), 2 QK^T MFMAs x4, exp2-domain online
// softmax with defer-max (THR=8), cvt_pk P-pack, 8 PV MFMAs.
// ---------------------------------------------------------------------------
__global__ __launch_bounds__(256) void attn_mfma(const ushort* __restrict__ Q,
                                                 const ushort* __restrict__ K,
                                                 const ushort* __restrict__ Vt,
                                                 ushort* __restrict__ O) {
  __shared__ ushort Ks[2][64][64];  // [buf][key][d]  128B rows, swizzled
  __shared__ ushort Vs[2][64][64];  // [buf][dq][key] 128B rows, swizzled
  __shared__ ushort Ps[4][16][64];  // [wave][q][key] 128B rows, swizzled

  const int t = threadIdx.x, lane = t & 63, ww = t >> 6;
  const int r16 = lane & 15, g = lane >> 4;

  const int bid = blockIdx.x;                    // 512 blocks
  const int xcd = bid & 7, idx = bid >> 3;       // idx 0..63
  const int bh = xcd * 4 + (idx & 3);            // 4 heads per XCD
  const int pp = idx >> 2;                       // 0..15
  const int b = bh >> 4, h = bh & 15;
  const size_t tokbase = (size_t)b * SS;
  const size_t hoff = (size_t)h * DQK;

  const int srow = t >> 3;                       // 0..31
  const int scol = (t & 7) * 16;                 // 0..112
  const char* Kb = (const char*)(K + tokbase * DD + hoff);
  const char* Vb = (const char*)(Vt + (size_t)bh * DQK * SS);
  const int sw = (r16 & 7) << 4;
  const float SCL = 0.125f * 1.44269504f;        // 1/sqrt(64) * log2(e)

#define STAGE(buf, j0)                                                        \
  {                                                                           \
    _Pragma("unroll")                                                         \
    for (int i = 0; i < 2; ++i) {                                             \
      const int R = i * 32 + srow;                                            \
      const int Cs = scol ^ ((R & 7) << 4);                                   \
      gload_lds16(Kb + ((size_t)((j0) + R) * DD) * 2 + Cs,                    \
                  (char*)&Ks[buf][0][0] + i * 4096 + ww * 1024);              \
      gload_lds16(Vb + ((size_t)R * SS + (j0)) * 2 + Cs,                      \
                  (char*)&Vs[buf][0][0] + i * 4096 + ww * 1024);              \
    }                                                                         \
  }

  for (int seg = 0; seg < 2; ++seg) {
    const int qb = seg ? (31 - pp) : pp;
    const int q0 = qb * 64 + ww * 16;
    const int nt = qb + 1;

    short8 qf[2];
#pragma unroll
    for (int kc = 0; kc < 2; ++kc)
      qf[kc] = *(const short8*)(Q + (tokbase + q0 + r16) * DD + hoff + kc * 32 + g * 8);

    f32x4 o[4];
#pragma unroll
    for (int dt = 0; dt < 4; ++dt) o[dt] = (f32x4){0.f, 0.f, 0.f, 0.f};
    float rm = -INFINITY, rl = 0.f;
    const int thr = q0 + r16 - g * 4;            // key tt*64+t2*16+r <= thr

    __syncthreads();                             // prev segment done with LDS
    STAGE(0, 0);
    int cur = 0;
    for (int tt = 0; tt < nt; ++tt) {
      asm volatile("s_waitcnt vmcnt(0)" ::: "memory");
      __syncthreads();
      if (tt + 1 < nt) STAGE(cur ^ 1, (tt + 1) * 64);

      const char* Kc = (const char*)&Ks[cur][0][0];
      const char* Vc = (const char*)&Vs[cur][0][0];

      // --- QK^T: S[key][q], q = r16 lane-resident ---
      f32x4 s4[4];
      __builtin_amdgcn_s_setprio(1);
#pragma unroll
      for (int t2 = 0; t2 < 4; ++t2) {
        const int rb = (t2 * 16 + r16) * 128;
        const short8 k0 = *(const short8*)(Kc + rb + ((g * 16) ^ sw));
        const short8 k1 = *(const short8*)(Kc + rb + ((64 + g * 16) ^ sw));
        f32x4 s = mfma16(k0, qf[0], (f32x4){0.f, 0.f, 0.f, 0.f});
        s4[t2] = mfma16(k1, qf[1], s);
      }
      __builtin_amdgcn_s_setprio(0);

      float sv[4][4];
      const bool last = (tt == nt - 1);
#pragma unroll
      for (int t2 = 0; t2 < 4; ++t2)
#pragma unroll
        for (int r = 0; r < 4; ++r) {
          float xv = s4[t2][r] * SCL;            // exp2 domain
          if (last) xv = (tt * 64 + t2 * 16 + r <= thr) ? xv : -INFINITY;
          sv[t2][r] = xv;
        }

      // --- online softmax (exp2 domain), defer-max THR=8 ---
      float mx = fmaxf(fmaxf(fmaxf(sv[0][0], sv[0][1]), fmaxf(sv[0][2], sv[0][3])),
                       fmaxf(fmaxf(sv[1][0], sv[1][1]), fmaxf(sv[1][2], sv[1][3])));
      mx = fmaxf(mx, fmaxf(fmaxf(fmaxf(sv[2][0], sv[2][1]), fmaxf(sv[2][2], sv[2][3])),
                           fmaxf(fmaxf(sv[3][0], sv[3][1]), fmaxf(sv[3][2], sv[3][3]))));
      mx = fmaxf(mx, __shfl_xor(mx, 16));
      mx = fmaxf(mx, __shfl_xor(mx, 32));
      if (!__all(mx - rm <= 8.f)) {
        const float mn = fmaxf(rm, mx);
        const float sc = __builtin_amdgcn_exp2f(rm - mn);
        rl *= sc;
#pragma unroll
        for (int dt = 0; dt < 4; ++dt) o[dt] *= sc;
        rm = mn;
      }
      float ps = 0.f;
#pragma unroll
      for (int t2 = 0; t2 < 4; ++t2) {
        const float p0 = __builtin_amdgcn_exp2f(sv[t2][0] - rm);
        const float p1 = __builtin_amdgcn_exp2f(sv[t2][1] - rm);
        const float p2 = __builtin_amdgcn_exp2f(sv[t2][2] - rm);
        const float p3 = __builtin_amdgcn_exp2f(sv[t2][3] - rm);
        ps += (p0 + p1) + (p2 + p3);
        uint2 pk;
        pk.x = cvt_pk_bf16(p0, p1);
        pk.y = cvt_pk_bf16(p2, p3);
        *(uint2*)((char*)&Ps[ww][0][0] + r16 * 128 + ((t2 * 32 + g * 8) ^ sw)) = pk;
      }
      ps += __shfl_xor(ps, 16);
      ps += __shfl_xor(ps, 32);
      rl += ps;

      // --- PV: O[dq][q] ---
      __builtin_amdgcn_s_setprio(1);
#pragma unroll
      for (int kc = 0; kc < 2; ++kc) {
        const short8 pb = *(const short8*)((const char*)&Ps[ww][0][0] + r16 * 128 +
                                           ((kc * 64 + g * 16) ^ sw));
#pragma unroll
        for (int dt = 0; dt < 4; ++dt) {
          const short8 vf = *(const short8*)(Vc + (dt * 16 + r16) * 128 +
                                             ((kc * 64 + g * 16) ^ sw));
          o[dt] = mfma16(vf, pb, o[dt]);
        }
      }
      __builtin_amdgcn_s_setprio(0);
      cur ^= 1;
    }

    // --- epilogue: lane (r16,g) holds O[dq=dt*16+g*4+r][q=r16] ---
    const float inv = 1.0f / rl;
#pragma unroll
    for (int dt = 0; dt < 4; ++dt) {
      uint2 st;
      st.x = cvt_pk_bf16(o[dt][0] * inv, o[dt][1] * inv);
      st.y = cvt_pk_bf16(o[dt][2] * inv, o[dt][3] * inv);
      *(uint2*)(O + (tokbase + q0 + r16) * DD + hoff + dt * 16 + g * 4) = st;
    }
  }
#undef STAGE
}

// ---------------------------------------------------------------------------
// Launch: wtrans -> LN -> fused QKV GEMM -> attn -> O-GEMM.
// ws: xn 8MB | q 8MB | k 8MB | vt 8MB | att 8MB | wt 16MB  (56MB)
// ---------------------------------------------------------------------------
extern "C" void kernel_launch(void* const* d_in, const int* in_sizes, int n_in,
                              void* d_out, int out_size, void* d_ws, size_t ws_size,
                              hipStream_t stream) {
  const float* x    = (const float*)d_in[0];
  const float* ln_g = (const float*)d_in[1];
  const float* ln_b = (const float*)d_in[2];
  const float* Wq   = (const float*)d_in[3];
  const float* bq   = (const float*)d_in[4];
  const float* Wk   = (const float*)d_in[5];
  const float* bk   = (const float*)d_in[6];
  const float* Wv   = (const float*)d_in[7];
  const float* bv   = (const float*)d_in[8];
  const float* Wo   = (const float*)d_in[9];
  const float* bo   = (const float*)d_in[10];
  float* out = (float*)d_out;

  ushort* ws  = (ushort*)d_ws;
  ushort* xn  = ws;
  ushort* qb  = xn + NE;
  ushort* kb  = qb + NE;
  ushort* vt  = kb + NE;
  ushort* ab  = vt + NE;
  ushort* wt  = ab + NE;               // 4 x [1024][1024] bf16
  ushort* wot = wt + (size_t)3 * DD * DD;

  wtrans<<<dim3(16, 16, 4), 256, 0, stream>>>(Wq, Wk, Wv, Wo, wt);
  ln_fwd<<<NROWS, 256, 0, stream>>>(x, ln_g, ln_b, xn);

  gemm_qkv<<<dim3(NROWS / 128, 24), 256, 0, stream>>>(xn, wt, bq, bk, bv,
                                                      qb, kb, vt);

  attn_mfma<<<BB * HH * (SS / 128), 256, 0, stream>>>(qb, kb, vt, ab);

  gemm_o<<<dim3(NROWS / 128, DD / 128), 256, 0, stream>>>(ab, wot, bo, x, out);
}

// Round 6
// 118.761 us; speedup vs baseline: 13.5900x; 1.0207x over previous
//
#include <hip/hip_runtime.h>
#include <math.h>

// Problem constants: B=2, S=2048, D=1024, H=16, DQ=64
#define BB 2
#define SS 2048
#define DD 1024
#define HH 16
#define DQK 64
#define NROWS (BB * SS)
#define NE ((size_t)BB * SS * DD)   // 4,194,304

using short8 = __attribute__((ext_vector_type(8))) short;
using f32x4  = __attribute__((ext_vector_type(4))) float;

__device__ __forceinline__ ushort f2bf(float f) {
  union { float f; unsigned u; } c; c.f = f;
  return (ushort)((c.u + 0x7fffu + ((c.u >> 16) & 1u)) >> 16);
}

__device__ __forceinline__ unsigned cvt_pk_bf16(float lo, float hi) {
  unsigned r;
  asm("v_cvt_pk_bf16_f32 %0, %1, %2" : "=v"(r) : "v"(lo), "v"(hi));
  return r;
}

__device__ __forceinline__ f32x4 mfma16(short8 a, short8 b, f32x4 c) {
  return __builtin_amdgcn_mfma_f32_16x16x32_bf16(a, b, c, 0, 0, 0);
}

typedef __attribute__((address_space(1))) const unsigned gas_u32;
typedef __attribute__((address_space(3))) unsigned las_u32;
__device__ __forceinline__ void gload_lds16(const void* g, void* l) {
  __builtin_amdgcn_global_load_lds((gas_u32*)g, (las_u32*)l, 16, 0, 0);
}

// ---------------------------------------------------------------------------
// LayerNorm -> bf16. One block per row.
// ---------------------------------------------------------------------------
__global__ __launch_bounds__(256) void ln_fwd(const float* __restrict__ x,
                                              const float* __restrict__ g,
                                              const float* __restrict__ bta,
                                              ushort* __restrict__ xn) {
  const int row = blockIdx.x;
  const int t = threadIdx.x;
  float4 v = ((const float4*)(x + (size_t)row * DD))[t];
  float s  = v.x + v.y + v.z + v.w;
  float ss = v.x * v.x + v.y * v.y + v.z * v.z + v.w * v.w;
#pragma unroll
  for (int off = 32; off > 0; off >>= 1) {
    s  += __shfl_xor(s, off);
    ss += __shfl_xor(ss, off);
  }
  __shared__ float red[8];
  const int wid = t >> 6, lane = t & 63;
  if (lane == 0) { red[wid] = s; red[4 + wid] = ss; }
  __syncthreads();
  const float stot  = red[0] + red[1] + red[2] + red[3];
  const float sstot = red[4] + red[5] + red[6] + red[7];
  const float mu  = stot * (1.0f / DD);
  const float var = sstot * (1.0f / DD) - mu * mu;
  const float inv = rsqrtf(var + 1e-5f);
  const float4 g4 = ((const float4*)g)[t];
  const float4 b4 = ((const float4*)bta)[t];
  ushort4 o;
  o.x = f2bf((v.x - mu) * inv * g4.x + b4.x);
  o.y = f2bf((v.y - mu) * inv * g4.y + b4.y);
  o.z = f2bf((v.z - mu) * inv * g4.z + b4.z);
  o.w = f2bf((v.w - mu) * inv * g4.w + b4.w);
  ((ushort4*)(xn + (size_t)row * DD))[t] = o;
}

// ---------------------------------------------------------------------------
// Transpose + bf16-cast the 4 weight matrices: W[K][N] fp32 -> Wt[N][K] bf16.
// ---------------------------------------------------------------------------
__global__ __launch_bounds__(256) void wtrans(const float* __restrict__ Wq,
                                              const float* __restrict__ Wk,
                                              const float* __restrict__ Wv,
                                              const float* __restrict__ Wo,
                                              ushort* __restrict__ wt) {
  const int z = blockIdx.z;
  const float* W = (z == 0) ? Wq : (z == 1) ? Wk : (z == 2) ? Wv : Wo;
  ushort* dst = wt + (size_t)z * DD * DD;
  __shared__ float tile[64][65];
  const int t = threadIdx.x;
  const int k0 = blockIdx.x * 64, n0 = blockIdx.y * 64;
  const int tr = t >> 4, tc = (t & 15) * 4;
#pragma unroll
  for (int rr = 0; rr < 64; rr += 16) {
    float4 v = *(const float4*)(W + (size_t)(k0 + rr + tr) * DD + n0 + tc);
    tile[rr + tr][tc + 0] = v.x;
    tile[rr + tr][tc + 1] = v.y;
    tile[rr + tr][tc + 2] = v.z;
    tile[rr + tr][tc + 3] = v.w;
  }
  __syncthreads();
#pragma unroll
  for (int rr = 0; rr < 64; rr += 16) {
    const int n = rr + tr;
    ushort4 o;
    o.x = f2bf(tile[tc + 0][n]);
    o.y = f2bf(tile[tc + 1][n]);
    o.z = f2bf(tile[tc + 2][n]);
    o.w = f2bf(tile[tc + 3][n]);
    *(ushort4*)(dst + (size_t)(n0 + n) * DD + k0 + tc) = o;
  }
}

// ---------------------------------------------------------------------------
// GEMM core. 128x128 tile, 4 waves, BK=32, global_load_lds staging (linear
// LDS dest, pre-swizzled global source; read-side XOR), double-buffered.
// ---------------------------------------------------------------------------
#define GEMM_CORE(Ag, Bg)                                                     \
  f32x4 acc[4][4];                                                            \
  _Pragma("unroll")                                                           \
  for (int m = 0; m < 4; ++m)                                                 \
    _Pragma("unroll")                                                         \
    for (int n = 0; n < 4; ++n) acc[m][n] = (f32x4){0.f, 0.f, 0.f, 0.f};     \
  const int cs = ((t & 3) * 16) ^ (((t >> 2) & 3) * 16);                      \
  const int fsw = (r16 & 3) * 16;                                             \
  {                                                                           \
    GSTAGE(Ag, Bg, 0, 0);                                                     \
    int cur = 0;                                                              \
    for (int k0 = 0; k0 < DD; k0 += 32) {                                     \
      asm volatile("s_waitcnt vmcnt(0)" ::: "memory");                        \
      __syncthreads();                                                        \
      if (k0 + 32 < DD) GSTAGE(Ag, Bg, cur ^ 1, k0 + 32);                     \
      const char* Ac = (const char*)&As[cur][0][0];                           \
      const char* Bc = (const char*)&Bs[cur][0][0];                           \
      short8 af[4], bf[4];                                                    \
      _Pragma("unroll")                                                       \
      for (int m = 0; m < 4; ++m)                                             \
        af[m] = *(const short8*)(Ac + (wr * 64 + m * 16 + r16) * 64 +         \
                                 ((g * 16) ^ fsw));                           \
      _Pragma("unroll")                                                       \
      for (int n = 0; n < 4; ++n)                                             \
        bf[n] = *(const short8*)(Bc + (wc * 64 + n * 16 + r16) * 64 +         \
                                 ((g * 16) ^ fsw));                           \
      _Pragma("unroll")                                                       \
      for (int m = 0; m < 4; ++m)                                             \
        _Pragma("unroll")                                                     \
        for (int n = 0; n < 4; ++n) acc[m][n] = mfma16(af[m], bf[n], acc[m][n]); \
      cur ^= 1;                                                               \
    }                                                                         \
  }

#define GSTAGE(Ag, Bg, buf, k0)                                               \
  {                                                                           \
    _Pragma("unroll")                                                         \
    for (int i = 0; i < 2; ++i) {                                             \
      gload_lds16(Ag + (size_t)(row0 + i * 64 + (t >> 2)) * (DD * 2) +        \
                      (k0) * 2 + cs,                                          \
                  (char*)&As[buf][0][0] + i * 4096 + t * 16);                 \
      gload_lds16(Bg + (size_t)(col0 + i * 64 + (t >> 2)) * (DD * 2) +        \
                      (k0) * 2 + cs,                                          \
                  (char*)&Bs[buf][0][0] + i * 4096 + t * 16);                 \
    }                                                                         \
  }

// Fused QKV projection. Q output is PRE-SCALED by 1/sqrt(64)*log2(e) so the
// attention kernel's scores land directly in the exp2 domain.
__global__ __launch_bounds__(256) void gemm_qkv(
    const ushort* __restrict__ A, const ushort* __restrict__ wt,
    const float* __restrict__ bq, const float* __restrict__ bk,
    const float* __restrict__ bv, ushort* __restrict__ qb,
    ushort* __restrict__ kb, ushort* __restrict__ vt) {
  __shared__ ushort As[2][128][32];
  __shared__ ushort Bs[2][128][32];
  const int t = threadIdx.x;
  const int lane = t & 63;
  const int w = t >> 6, wr = w >> 1, wc = w & 1;
  const int r16 = lane & 15, g = lane >> 4;
  const int row0 = blockIdx.x * 128;
  const int mat = blockIdx.y >> 3;
  const int col0 = (blockIdx.y & 7) * 128;
  const char* Ag = (const char*)A;
  const char* Bg = (const char*)(wt + (size_t)mat * DD * DD);
  const float* bias = (mat == 0) ? bq : (mat == 1) ? bk : bv;
  const float scl = (mat == 0) ? 0.125f * 1.44269504f : 1.0f;

  GEMM_CORE(Ag, Bg)

#pragma unroll
  for (int n = 0; n < 4; ++n) {
    const int c = col0 + wc * 64 + n * 16 + r16;
    const float bc = bias[c];
#pragma unroll
    for (int m = 0; m < 4; ++m) {
      const int rbase = row0 + wr * 64 + m * 16 + g * 4;
      if (mat < 2) {
        ushort* outb = (mat == 0) ? qb : kb;
#pragma unroll
        for (int e = 0; e < 4; ++e)
          outb[(size_t)(rbase + e) * DD + c] = f2bf((acc[m][n][e] + bc) * scl);
      } else {
        uint2 st;
        st.x = cvt_pk_bf16(acc[m][n][0] + bc, acc[m][n][1] + bc);
        st.y = cvt_pk_bf16(acc[m][n][2] + bc, acc[m][n][3] + bc);
        const size_t vrow = (size_t)((rbase >> 11) * HH + (c >> 6)) * DQK + (c & 63);
        *(uint2*)(vt + vrow * SS + (rbase & 2047)) = st;
      }
    }
  }
}

// Output projection: att @ Wo + bo + x -> fp32 out.
__global__ __launch_bounds__(256) void gemm_o(
    const ushort* __restrict__ A, const ushort* __restrict__ Bt,
    const float* __restrict__ bias, const float* __restrict__ resid,
    float* __restrict__ outf) {
  __shared__ ushort As[2][128][32];
  __shared__ ushort Bs[2][128][32];
  const int t = threadIdx.x;
  const int lane = t & 63;
  const int w = t >> 6, wr = w >> 1, wc = w & 1;
  const int r16 = lane & 15, g = lane >> 4;
  const int row0 = blockIdx.x * 128;
  const int col0 = blockIdx.y * 128;
  const char* Ag = (const char*)A;
  const char* Bg = (const char*)Bt;

  GEMM_CORE(Ag, Bg)

#pragma unroll
  for (int n = 0; n < 4; ++n) {
    const int c = col0 + wc * 64 + n * 16 + r16;
    const float bc = bias[c];
#pragma unroll
    for (int m = 0; m < 4; ++m) {
      const int rbase = row0 + wr * 64 + m * 16 + g * 4;
#pragma unroll
      for (int e = 0; e < 4; ++e) {
        const size_t idx = (size_t)(rbase + e) * DD + c;
        outf[idx] = acc[m][n][e] + bc + resid[idx];
      }
    }
  }
}

// ---------------------------------------------------------------------------
// MFMA flash attention (causal). One q-block (64 rows) per block, 1024 blocks
// (= 4 blocks/CU, LDS-exact), heavy-first. Per 64-key tile: K/V staged once
// via global_load_lds (swizzled source), 8 QK^T MFMAs, online softmax with
// per-lane PARTIAL l (cross-lane l-reduce once at end) and in-lane defer-max
// (cross-lane max-reduce only inside the rare rescale branch), 8 PV MFMAs.
// ---------------------------------------------------------------------------
__global__ __launch_bounds__(256) void attn_mfma(const ushort* __restrict__ Q,
                                                 const ushort* __restrict__ K,
                                                 const ushort* __restrict__ Vt,
                                                 ushort* __restrict__ O) {
  __shared__ ushort Ks[2][64][64];  // [buf][key][d]  128B rows, swizzled
  __shared__ ushort Vs[2][64][64];  // [buf][dq][key] 128B rows, swizzled
  __shared__ ushort Ps[4][16][64];  // [wave][q][key] 128B rows, swizzled

  const int t = threadIdx.x, lane = t & 63, ww = t >> 6;
  const int r16 = lane & 15, g = lane >> 4;

  const int bid = blockIdx.x;                    // 1024 blocks
  const int xcd = bid & 7, idx = bid >> 3;       // idx 0..127
  const int bh = xcd * 4 + (idx & 3);            // 4 heads per XCD
  const int qb = 31 - (idx >> 2);                // heavy first
  const int b = bh >> 4, h = bh & 15;
  const size_t tokbase = (size_t)b * SS;
  const size_t hoff = (size_t)h * DQK;
  const int q0 = qb * 64 + ww * 16;
  const int nt = qb + 1;

  const int srow = t >> 3;                       // 0..31
  const int scol = (t & 7) * 16;                 // 0..112
  const char* Kb = (const char*)(K + tokbase * DD + hoff);
  const char* Vb = (const char*)(Vt + (size_t)bh * DQK * SS);
  const int sw = (r16 & 7) << 4;

#define STAGE(buf, j0)                                                        \
  {                                                                           \
    _Pragma("unroll")                                                         \
    for (int i = 0; i < 2; ++i) {                                             \
      const int R = i * 32 + srow;                                            \
      const int Cs = scol ^ ((R & 7) << 4);                                   \
      gload_lds16(Kb + ((size_t)((j0) + R) * DD) * 2 + Cs,                    \
                  (char*)&Ks[buf][0][0] + i * 4096 + ww * 1024);              \
      gload_lds16(Vb + ((size_t)R * SS + (j0)) * 2 + Cs,                      \
                  (char*)&Vs[buf][0][0] + i * 4096 + ww * 1024);              \
    }                                                                         \
  }

  // Q fragments (B-operand, pre-scaled): col=q=r16, k = kc*32 + g*8 + e
  short8 qf[2];
#pragma unroll
  for (int kc = 0; kc < 2; ++kc)
    qf[kc] = *(const short8*)(Q + (tokbase + q0 + r16) * DD + hoff + kc * 32 + g * 8);

  f32x4 o[4];
#pragma unroll
  for (int dt = 0; dt < 4; ++dt) o[dt] = (f32x4){0.f, 0.f, 0.f, 0.f};
  float rm = -INFINITY, rl = 0.f;                // rl is a per-lane PARTIAL
  const int thr = q0 + r16 - g * 4;              // key tt*64+t2*16+r <= thr

  STAGE(0, 0);
  int cur = 0;
  for (int tt = 0; tt < nt; ++tt) {
    asm volatile("s_waitcnt vmcnt(0)" ::: "memory");
    __syncthreads();
    if (tt + 1 < nt) STAGE(cur ^ 1, (tt + 1) * 64);

    const char* Kc = (const char*)&Ks[cur][0][0];
    const char* Vc = (const char*)&Vs[cur][0][0];

    // --- QK^T: S[key][q], q = r16 lane-resident; exp2-domain scores ---
    f32x4 s4[4];
    __builtin_amdgcn_s_setprio(1);
#pragma unroll
    for (int t2 = 0; t2 < 4; ++t2) {
      const int rb = (t2 * 16 + r16) * 128;
      const short8 k0 = *(const short8*)(Kc + rb + ((g * 16) ^ sw));
      const short8 k1 = *(const short8*)(Kc + rb + ((64 + g * 16) ^ sw));
      f32x4 s = mfma16(k0, qf[0], (f32x4){0.f, 0.f, 0.f, 0.f});
      s4[t2] = mfma16(k1, qf[1], s);
    }
    __builtin_amdgcn_s_setprio(0);

    if (tt == nt - 1) {                          // block-uniform: mask last tile
#pragma unroll
      for (int t2 = 0; t2 < 4; ++t2)
#pragma unroll
        for (int r = 0; r < 4; ++r)
          s4[t2][r] = (tt * 64 + t2 * 16 + r <= thr) ? s4[t2][r] : -INFINITY;
    }

    // --- in-lane max over this lane's 16 keys ---
    float mx = fmaxf(
        fmaxf(fmaxf(fmaxf(s4[0][0], s4[0][1]), fmaxf(s4[0][2], s4[0][3])),
              fmaxf(fmaxf(s4[1][0], s4[1][1]), fmaxf(s4[1][2], s4[1][3]))),
        fmaxf(fmaxf(fmaxf(s4[2][0], s4[2][1]), fmaxf(s4[2][2], s4[2][3])),
              fmaxf(fmaxf(s4[3][0], s4[3][1]), fmaxf(s4[3][2], s4[3][3]))));

    // --- defer-max: rescale only when some lane's max grew past rm+8.
    // First tile: rm=-inf makes the compare fail (inf/NaN) -> rescale taken.
    if (!__all(mx - rm <= 8.f)) {
      float mf = fmaxf(mx, __shfl_xor(mx, 16));
      mf = fmaxf(mf, __shfl_xor(mf, 32));        // column max over 64 keys
      const float mn = fmaxf(rm, mf);
      const float sc = __builtin_amdgcn_exp2f(rm - mn);
      rl *= sc;
#pragma unroll
      for (int dt = 0; dt < 4; ++dt) o[dt] *= sc;
      rm = mn;
    }

    // --- P = exp2(S - rm); accumulate PARTIAL l; pack to LDS ---
#pragma unroll
    for (int t2 = 0; t2 < 4; ++t2) {
      const float p0 = __builtin_amdgcn_exp2f(s4[t2][0] - rm);
      const float p1 = __builtin_amdgcn_exp2f(s4[t2][1] - rm);
      const float p2 = __builtin_amdgcn_exp2f(s4[t2][2] - rm);
      const float p3 = __builtin_amdgcn_exp2f(s4[t2][3] - rm);
      rl += (p0 + p1) + (p2 + p3);
      uint2 pk;
      pk.x = cvt_pk_bf16(p0, p1);
      pk.y = cvt_pk_bf16(p2, p3);
      *(uint2*)((char*)&Ps[ww][0][0] + r16 * 128 + ((t2 * 32 + g * 8) ^ sw)) = pk;
    }

    // --- PV: O[dq][q] ---
    __builtin_amdgcn_s_setprio(1);
#pragma unroll
    for (int kc = 0; kc < 2; ++kc) {
      const short8 pb = *(const short8*)((const char*)&Ps[ww][0][0] + r16 * 128 +
                                         ((kc * 64 + g * 16) ^ sw));
#pragma unroll
      for (int dt = 0; dt < 4; ++dt) {
        const short8 vf = *(const short8*)(Vc + (dt * 16 + r16) * 128 +
                                           ((kc * 64 + g * 16) ^ sw));
        o[dt] = mfma16(vf, pb, o[dt]);
      }
    }
    __builtin_amdgcn_s_setprio(0);
    cur ^= 1;
  }
#undef STAGE

  // --- cross-lane l-reduction, once ---
  rl += __shfl_xor(rl, 16);
  rl += __shfl_xor(rl, 32);
  const float inv = 1.0f / rl;
#pragma unroll
  for (int dt = 0; dt < 4; ++dt) {
    uint2 st;
    st.x = cvt_pk_bf16(o[dt][0] * inv, o[dt][1] * inv);
    st.y = cvt_pk_bf16(o[dt][2] * inv, o[dt][3] * inv);
    *(uint2*)(O + (tokbase + q0 + r16) * DD + hoff + dt * 16 + g * 4) = st;
  }
}

// ---------------------------------------------------------------------------
// Launch: wtrans -> LN -> fused QKV GEMM -> attn -> O-GEMM.
// ws: xn 8MB | q 8MB | k 8MB | vt 8MB | att 8MB | wt 16MB  (56MB)
// ---------------------------------------------------------------------------
extern "C" void kernel_launch(void* const* d_in, const int* in_sizes, int n_in,
                              void* d_out, int out_size, void* d_ws, size_t ws_size,
                              hipStream_t stream) {
  const float* x    = (const float*)d_in[0];
  const float* ln_g = (const float*)d_in[1];
  const float* ln_b = (const float*)d_in[2];
  const float* Wq   = (const float*)d_in[3];
  const float* bq   = (const float*)d_in[4];
  const float* Wk   = (const float*)d_in[5];
  const float* bk   = (const float*)d_in[6];
  const float* Wv   = (const float*)d_in[7];
  const float* bv   = (const float*)d_in[8];
  const float* Wo   = (const float*)d_in[9];
  const float* bo   = (const float*)d_in[10];
  float* out = (float*)d_out;

  ushort* ws  = (ushort*)d_ws;
  ushort* xn  = ws;
  ushort* qb  = xn + NE;
  ushort* kb  = qb + NE;
  ushort* vt  = kb + NE;
  ushort* ab  = vt + NE;
  ushort* wt  = ab + NE;               // 4 x [1024][1024] bf16
  ushort* wot = wt + (size_t)3 * DD * DD;

  wtrans<<<dim3(16, 16, 4), 256, 0, stream>>>(Wq, Wk, Wv, Wo, wt);
  ln_fwd<<<NROWS, 256, 0, stream>>>(x, ln_g, ln_b, xn);

  gemm_qkv<<<dim3(NROWS / 128, 24), 256, 0, stream>>>(xn, wt, bq, bk, bv,
                                                      qb, kb, vt);

  attn_mfma<<<BB * HH * (SS / 64), 256, 0, stream>>>(qb, kb, vt, ab);

  gemm_o<<<dim3(NROWS / 128, DD / 128), 256, 0, stream>>>(ab, wot, bo, x, out);
}

// Round 7
// 115.022 us; speedup vs baseline: 14.0317x; 1.0325x over previous
//
#include <hip/hip_runtime.h>
#include <math.h>

// Problem constants: B=2, S=2048, D=1024, H=16, DQ=64
#define BB 2
#define SS 2048
#define DD 1024
#define HH 16
#define DQK 64
#define NROWS (BB * SS)
#define NE ((size_t)BB * SS * DD)   // 4,194,304

using short8 = __attribute__((ext_vector_type(8))) short;
using f32x4  = __attribute__((ext_vector_type(4))) float;

__device__ __forceinline__ ushort f2bf(float f) {
  union { float f; unsigned u; } c; c.f = f;
  return (ushort)((c.u + 0x7fffu + ((c.u >> 16) & 1u)) >> 16);
}

__device__ __forceinline__ unsigned cvt_pk_bf16(float lo, float hi) {
  unsigned r;
  asm("v_cvt_pk_bf16_f32 %0, %1, %2" : "=v"(r) : "v"(lo), "v"(hi));
  return r;
}

__device__ __forceinline__ f32x4 mfma16(short8 a, short8 b, f32x4 c) {
  return __builtin_amdgcn_mfma_f32_16x16x32_bf16(a, b, c, 0, 0, 0);
}

typedef __attribute__((address_space(1))) const unsigned gas_u32;
typedef __attribute__((address_space(3))) unsigned las_u32;
__device__ __forceinline__ void gload_lds16(const void* g, void* l) {
  __builtin_amdgcn_global_load_lds((gas_u32*)g, (las_u32*)l, 16, 0, 0);
}

// ---------------------------------------------------------------------------
// Fused prepass: blocks [0,4096) do LayerNorm->bf16 (one row each);
// blocks [4096,5120) transpose+cast the 4 weight matrices to Wt[N][K] bf16.
// ---------------------------------------------------------------------------
__global__ __launch_bounds__(256) void prep(const float* __restrict__ x,
                                            const float* __restrict__ g,
                                            const float* __restrict__ bta,
                                            ushort* __restrict__ xn,
                                            const float* __restrict__ Wq,
                                            const float* __restrict__ Wk,
                                            const float* __restrict__ Wv,
                                            const float* __restrict__ Wo,
                                            ushort* __restrict__ wt) {
  __shared__ float tile[64][65];
  const int t = threadIdx.x;
  if (blockIdx.x < NROWS) {
    const int row = blockIdx.x;
    float4 v = ((const float4*)(x + (size_t)row * DD))[t];
    float s  = v.x + v.y + v.z + v.w;
    float ss = v.x * v.x + v.y * v.y + v.z * v.z + v.w * v.w;
#pragma unroll
    for (int off = 32; off > 0; off >>= 1) {
      s  += __shfl_xor(s, off);
      ss += __shfl_xor(ss, off);
    }
    const int wid = t >> 6, lane = t & 63;
    if (lane == 0) { tile[0][wid] = s; tile[0][4 + wid] = ss; }
    __syncthreads();
    const float stot  = tile[0][0] + tile[0][1] + tile[0][2] + tile[0][3];
    const float sstot = tile[0][4] + tile[0][5] + tile[0][6] + tile[0][7];
    const float mu  = stot * (1.0f / DD);
    const float var = sstot * (1.0f / DD) - mu * mu;
    const float inv = rsqrtf(var + 1e-5f);
    const float4 g4 = ((const float4*)g)[t];
    const float4 b4 = ((const float4*)bta)[t];
    ushort4 o;
    o.x = f2bf((v.x - mu) * inv * g4.x + b4.x);
    o.y = f2bf((v.y - mu) * inv * g4.y + b4.y);
    o.z = f2bf((v.z - mu) * inv * g4.z + b4.z);
    o.w = f2bf((v.w - mu) * inv * g4.w + b4.w);
    ((ushort4*)(xn + (size_t)row * DD))[t] = o;
  } else {
    const int wb = blockIdx.x - NROWS;        // 0..1023
    const int z = wb >> 8;                    // matrix id
    const int k0 = (wb & 15) * 64, n0 = ((wb >> 4) & 15) * 64;
    const float* W = (z == 0) ? Wq : (z == 1) ? Wk : (z == 2) ? Wv : Wo;
    ushort* dst = wt + (size_t)z * DD * DD;
    const int tr = t >> 4, tc = (t & 15) * 4;
#pragma unroll
    for (int rr = 0; rr < 64; rr += 16) {
      float4 v = *(const float4*)(W + (size_t)(k0 + rr + tr) * DD + n0 + tc);
      tile[rr + tr][tc + 0] = v.x;
      tile[rr + tr][tc + 1] = v.y;
      tile[rr + tr][tc + 2] = v.z;
      tile[rr + tr][tc + 3] = v.w;
    }
    __syncthreads();
#pragma unroll
    for (int rr = 0; rr < 64; rr += 16) {
      const int n = rr + tr;
      ushort4 o;
      o.x = f2bf(tile[tc + 0][n]);
      o.y = f2bf(tile[tc + 1][n]);
      o.z = f2bf(tile[tc + 2][n]);
      o.w = f2bf(tile[tc + 3][n]);
      *(ushort4*)(dst + (size_t)(n0 + n) * DD + k0 + tc) = o;
    }
  }
}

// ---------------------------------------------------------------------------
// GEMM core. 128x128 tile, 4 waves, BK=32, global_load_lds staging (linear
// LDS dest, pre-swizzled global source; read-side XOR), double-buffered.
// ---------------------------------------------------------------------------
#define GEMM_CORE(Ag, Bg)                                                     \
  f32x4 acc[4][4];                                                            \
  _Pragma("unroll")                                                           \
  for (int m = 0; m < 4; ++m)                                                 \
    _Pragma("unroll")                                                         \
    for (int n = 0; n < 4; ++n) acc[m][n] = (f32x4){0.f, 0.f, 0.f, 0.f};     \
  const int cs = ((t & 3) * 16) ^ (((t >> 2) & 3) * 16);                      \
  const int fsw = (r16 & 3) * 16;                                             \
  {                                                                           \
    GSTAGE(Ag, Bg, 0, 0);                                                     \
    int cur = 0;                                                              \
    for (int k0 = 0; k0 < DD; k0 += 32) {                                     \
      asm volatile("s_waitcnt vmcnt(0)" ::: "memory");                        \
      __syncthreads();                                                        \
      if (k0 + 32 < DD) GSTAGE(Ag, Bg, cur ^ 1, k0 + 32);                     \
      const char* Ac = (const char*)&As[cur][0][0];                           \
      const char* Bc = (const char*)&Bs[cur][0][0];                           \
      short8 af[4], bf[4];                                                    \
      _Pragma("unroll")                                                       \
      for (int m = 0; m < 4; ++m)                                             \
        af[m] = *(const short8*)(Ac + (wr * 64 + m * 16 + r16) * 64 +         \
                                 ((g * 16) ^ fsw));                           \
      _Pragma("unroll")                                                       \
      for (int n = 0; n < 4; ++n)                                             \
        bf[n] = *(const short8*)(Bc + (wc * 64 + n * 16 + r16) * 64 +         \
                                 ((g * 16) ^ fsw));                           \
      _Pragma("unroll")                                                       \
      for (int m = 0; m < 4; ++m)                                             \
        _Pragma("unroll")                                                     \
        for (int n = 0; n < 4; ++n) acc[m][n] = mfma16(af[m], bf[n], acc[m][n]); \
      cur ^= 1;                                                               \
    }                                                                         \
  }

#define GSTAGE(Ag, Bg, buf, k0)                                               \
  {                                                                           \
    _Pragma("unroll")                                                         \
    for (int i = 0; i < 2; ++i) {                                             \
      gload_lds16(Ag + (size_t)(row0 + i * 64 + (t >> 2)) * (DD * 2) +        \
                      (k0) * 2 + cs,                                          \
                  (char*)&As[buf][0][0] + i * 4096 + t * 16);                 \
      gload_lds16(Bg + (size_t)(col0 + i * 64 + (t >> 2)) * (DD * 2) +        \
                      (k0) * 2 + cs,                                          \
                  (char*)&Bs[buf][0][0] + i * 4096 + t * 16);                 \
    }                                                                         \
  }

// Fused QKV projection. Q output is PRE-SCALED by 1/sqrt(64)*log2(e) so the
// attention kernel's scores land directly in the exp2 domain.
__global__ __launch_bounds__(256) void gemm_qkv(
    const ushort* __restrict__ A, const ushort* __restrict__ wt,
    const float* __restrict__ bq, const float* __restrict__ bk,
    const float* __restrict__ bv, ushort* __restrict__ qb,
    ushort* __restrict__ kb, ushort* __restrict__ vt) {
  __shared__ ushort As[2][128][32];
  __shared__ ushort Bs[2][128][32];
  const int t = threadIdx.x;
  const int lane = t & 63;
  const int w = t >> 6, wr = w >> 1, wc = w & 1;
  const int r16 = lane & 15, g = lane >> 4;
  const int row0 = blockIdx.x * 128;
  const int mat = blockIdx.y >> 3;
  const int col0 = (blockIdx.y & 7) * 128;
  const char* Ag = (const char*)A;
  const char* Bg = (const char*)(wt + (size_t)mat * DD * DD);
  const float* bias = (mat == 0) ? bq : (mat == 1) ? bk : bv;
  const float scl = (mat == 0) ? 0.125f * 1.44269504f : 1.0f;

  GEMM_CORE(Ag, Bg)

#pragma unroll
  for (int n = 0; n < 4; ++n) {
    const int c = col0 + wc * 64 + n * 16 + r16;
    const float bc = bias[c];
#pragma unroll
    for (int m = 0; m < 4; ++m) {
      const int rbase = row0 + wr * 64 + m * 16 + g * 4;
      if (mat < 2) {
        ushort* outb = (mat == 0) ? qb : kb;
#pragma unroll
        for (int e = 0; e < 4; ++e)
          outb[(size_t)(rbase + e) * DD + c] = f2bf((acc[m][n][e] + bc) * scl);
      } else {
        uint2 st;
        st.x = cvt_pk_bf16(acc[m][n][0] + bc, acc[m][n][1] + bc);
        st.y = cvt_pk_bf16(acc[m][n][2] + bc, acc[m][n][3] + bc);
        const size_t vrow = (size_t)((rbase >> 11) * HH + (c >> 6)) * DQK + (c & 63);
        *(uint2*)(vt + vrow * SS + (rbase & 2047)) = st;
      }
    }
  }
}

// Output projection: att @ Wo + bo + x -> fp32 out.
__global__ __launch_bounds__(256) void gemm_o(
    const ushort* __restrict__ A, const ushort* __restrict__ Bt,
    const float* __restrict__ bias, const float* __restrict__ resid,
    float* __restrict__ outf) {
  __shared__ ushort As[2][128][32];
  __shared__ ushort Bs[2][128][32];
  const int t = threadIdx.x;
  const int lane = t & 63;
  const int w = t >> 6, wr = w >> 1, wc = w & 1;
  const int r16 = lane & 15, g = lane >> 4;
  const int row0 = blockIdx.x * 128;
  const int col0 = blockIdx.y * 128;
  const char* Ag = (const char*)A;
  const char* Bg = (const char*)Bt;

  GEMM_CORE(Ag, Bg)

#pragma unroll
  for (int n = 0; n < 4; ++n) {
    const int c = col0 + wc * 64 + n * 16 + r16;
    const float bc = bias[c];
#pragma unroll
    for (int m = 0; m < 4; ++m) {
      const int rbase = row0 + wr * 64 + m * 16 + g * 4;
#pragma unroll
      for (int e = 0; e < 4; ++e) {
        const size_t idx = (size_t)(rbase + e) * DD + c;
        outf[idx] = acc[m][n][e] + bc + resid[idx];
      }
    }
  }
}

// ---------------------------------------------------------------------------
// MFMA flash attention (causal). One 64-row q-block per block; 1024 blocks.
// KEY RELABELING: QK^T A-row s of MFMA t2 holds physical key
//   key = (t2&1)*4 + (s&3) + (s>>2)*8 + (t2>>1)*32
// (a permuted K-row read from LDS - free). Then the C/D output lane (r16,g)
// holds exactly keys {kc*32+g*8+e} = the PV B-fragment layout, so P never
// touches LDS: 8 in-lane cvt_pk -> short8 -> PV MFMA. LDS = 32 KB.
// Balanced map: bid=[j:2][m:3][bh:5]; CU slot (bid%256) serves one head with
// qb in {31-m, m, 23-m, 8+m}: per-CU work is constant (66 tiles).
// ---------------------------------------------------------------------------
__global__ __launch_bounds__(256) void attn_mfma(const ushort* __restrict__ Q,
                                                 const ushort* __restrict__ K,
                                                 const ushort* __restrict__ Vt,
                                                 ushort* __restrict__ O) {
  __shared__ ushort Ks[2][64][64];  // [buf][key][d]  128B rows, swizzled
  __shared__ ushort Vs[2][64][64];  // [buf][dq][key] 128B rows, swizzled

  const int t = threadIdx.x, lane = t & 63, ww = t >> 6;
  const int r16 = lane & 15, g = lane >> 4;

  const int bid = blockIdx.x;                    // 1024 blocks
  const int xcd = bid & 7;
  const int bh = xcd * 4 + ((bid >> 3) & 3);     // 4 heads per XCD
  const int m = (bid >> 5) & 7;
  const int j = bid >> 8;                        // 0..3
  const int qb = (j == 0) ? (31 - m) : (j == 1) ? m : (j == 2) ? (23 - m) : (8 + m);
  const int b = bh >> 4, h = bh & 15;
  const size_t tokbase = (size_t)b * SS;
  const size_t hoff = (size_t)h * DQK;
  const int q0 = qb * 64 + ww * 16;
  const int nt = qb + 1;

  const int srow = t >> 3;                       // 0..31
  const int scol = (t & 7) * 16;                 // 0..112
  const char* Kb = (const char*)(K + tokbase * DD + hoff);
  const char* Vb = (const char*)(Vt + (size_t)bh * DQK * SS);
  const int sw = (r16 & 7) << 4;                 // V-read swizzle
  const int rlo = (r16 & 3) + ((r16 >> 2) << 3); // K-row permutation base

#define STAGE(buf, j0)                                                        \
  {                                                                           \
    _Pragma("unroll")                                                         \
    for (int i = 0; i < 2; ++i) {                                             \
      const int R = i * 32 + srow;                                            \
      const int Cs = scol ^ ((R & 7) << 4);                                   \
      gload_lds16(Kb + ((size_t)((j0) + R) * DD) * 2 + Cs,                    \
                  (char*)&Ks[buf][0][0] + i * 4096 + ww * 1024);              \
      gload_lds16(Vb + ((size_t)R * SS + (j0)) * 2 + Cs,                      \
                  (char*)&Vs[buf][0][0] + i * 4096 + ww * 1024);              \
    }                                                                         \
  }

  // Q fragments (B-operand, pre-scaled): col=q=r16, k = kc*32 + g*8 + e
  short8 qf[2];
#pragma unroll
  for (int kc = 0; kc < 2; ++kc)
    qf[kc] = *(const short8*)(Q + (tokbase + q0 + r16) * DD + hoff + kc * 32 + g * 8);

  f32x4 o[4];
#pragma unroll
  for (int dt = 0; dt < 4; ++dt) o[dt] = (f32x4){0.f, 0.f, 0.f, 0.f};
  float rm = -INFINITY, rl = 0.f;                // rl is a per-lane PARTIAL

  STAGE(0, 0);
  int cur = 0;
  for (int tt = 0; tt < nt; ++tt) {
    asm volatile("s_waitcnt vmcnt(0)" ::: "memory");
    __syncthreads();
    if (tt + 1 < nt) STAGE(cur ^ 1, (tt + 1) * 64);

    const char* Kc = (const char*)&Ks[cur][0][0];
    const char* Vc = (const char*)&Vs[cur][0][0];

    // --- QK^T with permuted K-rows: lane (r16,g) of s4[t2] holds physical
    // keys {(t2&1)*4 + r + g*8 + (t2>>1)*32}, q = r16 ---
    f32x4 s4[4];
    __builtin_amdgcn_s_setprio(1);
#pragma unroll
    for (int t2 = 0; t2 < 4; ++t2) {
      const int kk = rlo + (t2 & 1) * 4 + (t2 >> 1) * 32;
      const int sk = (kk & 7) << 4;
      const int rb = kk * 128;
      const short8 k0 = *(const short8*)(Kc + rb + ((g * 16) ^ sk));
      const short8 k1 = *(const short8*)(Kc + rb + ((64 + g * 16) ^ sk));
      f32x4 s = mfma16(k0, qf[0], (f32x4){0.f, 0.f, 0.f, 0.f});
      s4[t2] = mfma16(k1, qf[1], s);
    }
    __builtin_amdgcn_s_setprio(0);

    if (tt == nt - 1) {                          // mask last tile only
      const int thrl = q0 + r16 - g * 8 - tt * 64;
#pragma unroll
      for (int t2 = 0; t2 < 4; ++t2) {
        const int bb = (t2 & 1) * 4 + (t2 >> 1) * 32;
#pragma unroll
        for (int r = 0; r < 4; ++r)
          s4[t2][r] = (bb + r <= thrl) ? s4[t2][r] : -INFINITY;
      }
    }

    // --- in-lane max over this lane's 16 keys ---
    float mx = fmaxf(
        fmaxf(fmaxf(fmaxf(s4[0][0], s4[0][1]), fmaxf(s4[0][2], s4[0][3])),
              fmaxf(fmaxf(s4[1][0], s4[1][1]), fmaxf(s4[1][2], s4[1][3]))),
        fmaxf(fmaxf(fmaxf(s4[2][0], s4[2][1]), fmaxf(s4[2][2], s4[2][3])),
              fmaxf(fmaxf(s4[3][0], s4[3][1]), fmaxf(s4[3][2], s4[3][3]))));

    // --- defer-max: rescale only when some lane's max grew past rm+8 ---
    if (!__all(mx - rm <= 8.f)) {
      float mf = fmaxf(mx, __shfl_xor(mx, 16));
      mf = fmaxf(mf, __shfl_xor(mf, 32));        // column max over 64 keys
      const float mn = fmaxf(rm, mf);
      const float sc = __builtin_amdgcn_exp2f(rm - mn);
      rl *= sc;
#pragma unroll
      for (int dt = 0; dt < 4; ++dt) o[dt] *= sc;
      rm = mn;
    }

    // --- P = exp2(S - rm), packed IN-LANE directly to PV B-frags ---
    union { unsigned u[4]; short8 s; } pbu[2];
#pragma unroll
    for (int t2 = 0; t2 < 4; ++t2) {
      const float p0 = __builtin_amdgcn_exp2f(s4[t2][0] - rm);
      const float p1 = __builtin_amdgcn_exp2f(s4[t2][1] - rm);
      const float p2 = __builtin_amdgcn_exp2f(s4[t2][2] - rm);
      const float p3 = __builtin_amdgcn_exp2f(s4[t2][3] - rm);
      rl += (p0 + p1) + (p2 + p3);
      pbu[t2 >> 1].u[(t2 & 1) * 2 + 0] = cvt_pk_bf16(p0, p1);
      pbu[t2 >> 1].u[(t2 & 1) * 2 + 1] = cvt_pk_bf16(p2, p3);
    }

    // --- PV: O[dq][q] ---
    __builtin_amdgcn_s_setprio(1);
#pragma unroll
    for (int kc = 0; kc < 2; ++kc) {
#pragma unroll
      for (int dt = 0; dt < 4; ++dt) {
        const short8 vf = *(const short8*)(Vc + (dt * 16 + r16) * 128 +
                                           ((kc * 64 + g * 16) ^ sw));
        o[dt] = mfma16(vf, pbu[kc].s, o[dt]);
      }
    }
    __builtin_amdgcn_s_setprio(0);
    cur ^= 1;
  }
#undef STAGE

  // --- cross-lane l-reduction, once ---
  rl += __shfl_xor(rl, 16);
  rl += __shfl_xor(rl, 32);
  const float inv = 1.0f / rl;
#pragma unroll
  for (int dt = 0; dt < 4; ++dt) {
    uint2 st;
    st.x = cvt_pk_bf16(o[dt][0] * inv, o[dt][1] * inv);
    st.y = cvt_pk_bf16(o[dt][2] * inv, o[dt][3] * inv);
    *(uint2*)(O + (tokbase + q0 + r16) * DD + hoff + dt * 16 + g * 4) = st;
  }
}

// ---------------------------------------------------------------------------
// Launch: prep (LN + wtrans fused) -> fused QKV GEMM -> attn -> O-GEMM.
// ws: xn 8MB | q 8MB | k 8MB | vt 8MB | att 8MB | wt 16MB  (56MB)
// ---------------------------------------------------------------------------
extern "C" void kernel_launch(void* const* d_in, const int* in_sizes, int n_in,
                              void* d_out, int out_size, void* d_ws, size_t ws_size,
                              hipStream_t stream) {
  const float* x    = (const float*)d_in[0];
  const float* ln_g = (const float*)d_in[1];
  const float* ln_b = (const float*)d_in[2];
  const float* Wq   = (const float*)d_in[3];
  const float* bq   = (const float*)d_in[4];
  const float* Wk   = (const float*)d_in[5];
  const float* bk   = (const float*)d_in[6];
  const float* Wv   = (const float*)d_in[7];
  const float* bv   = (const float*)d_in[8];
  const float* Wo   = (const float*)d_in[9];
  const float* bo   = (const float*)d_in[10];
  float* out = (float*)d_out;

  ushort* ws  = (ushort*)d_ws;
  ushort* xn  = ws;
  ushort* qb  = xn + NE;
  ushort* kb  = qb + NE;
  ushort* vt  = kb + NE;
  ushort* ab  = vt + NE;
  ushort* wt  = ab + NE;               // 4 x [1024][1024] bf16
  ushort* wot = wt + (size_t)3 * DD * DD;

  prep<<<NROWS + 1024, 256, 0, stream>>>(x, ln_g, ln_b, xn, Wq, Wk, Wv, Wo, wt);

  gemm_qkv<<<dim3(NROWS / 128, 24), 256, 0, stream>>>(xn, wt, bq, bk, bv,
                                                      qb, kb, vt);

  attn_mfma<<<BB * HH * (SS / 64), 256, 0, stream>>>(qb, kb, vt, ab);

  gemm_o<<<dim3(NROWS / 128, DD / 128), 256, 0, stream>>>(ab, wot, bo, x, out);
}

// Round 8
// 107.807 us; speedup vs baseline: 14.9709x; 1.0669x over previous
//
#include <hip/hip_runtime.h>
#include <math.h>

// Problem constants: B=2, S=2048, D=1024, H=16, DQ=64
#define BB 2
#define SS 2048
#define DD 1024
#define HH 16
#define DQK 64
#define NROWS (BB * SS)
#define NE ((size_t)BB * SS * DD)   // 4,194,304

using short8 = __attribute__((ext_vector_type(8))) short;
using f32x4  = __attribute__((ext_vector_type(4))) float;

__device__ __forceinline__ ushort f2bf(float f) {
  union { float f; unsigned u; } c; c.f = f;
  return (ushort)((c.u + 0x7fffu + ((c.u >> 16) & 1u)) >> 16);
}

__device__ __forceinline__ unsigned cvt_pk_bf16(float lo, float hi) {
  unsigned r;
  asm("v_cvt_pk_bf16_f32 %0, %1, %2" : "=v"(r) : "v"(lo), "v"(hi));
  return r;
}

__device__ __forceinline__ f32x4 mfma16(short8 a, short8 b, f32x4 c) {
  return __builtin_amdgcn_mfma_f32_16x16x32_bf16(a, b, c, 0, 0, 0);
}

typedef __attribute__((address_space(1))) const unsigned gas_u32;
typedef __attribute__((address_space(3))) unsigned las_u32;
__device__ __forceinline__ void gload_lds16(const void* g, void* l) {
  __builtin_amdgcn_global_load_lds((gas_u32*)g, (las_u32*)l, 16, 0, 0);
}

// ---------------------------------------------------------------------------
// Fused prepass: blocks [0,4096) do LayerNorm->bf16 (one row each);
// blocks [4096,5120) transpose+cast the 4 weight matrices to Wt[N][K] bf16.
// ---------------------------------------------------------------------------
__global__ __launch_bounds__(256) void prep(const float* __restrict__ x,
                                            const float* __restrict__ g,
                                            const float* __restrict__ bta,
                                            ushort* __restrict__ xn,
                                            const float* __restrict__ Wq,
                                            const float* __restrict__ Wk,
                                            const float* __restrict__ Wv,
                                            const float* __restrict__ Wo,
                                            ushort* __restrict__ wt) {
  __shared__ float tile[64][65];
  const int t = threadIdx.x;
  if (blockIdx.x < NROWS) {
    const int row = blockIdx.x;
    float4 v = ((const float4*)(x + (size_t)row * DD))[t];
    float s  = v.x + v.y + v.z + v.w;
    float ss = v.x * v.x + v.y * v.y + v.z * v.z + v.w * v.w;
#pragma unroll
    for (int off = 32; off > 0; off >>= 1) {
      s  += __shfl_xor(s, off);
      ss += __shfl_xor(ss, off);
    }
    const int wid = t >> 6, lane = t & 63;
    if (lane == 0) { tile[0][wid] = s; tile[0][4 + wid] = ss; }
    __syncthreads();
    const float stot  = tile[0][0] + tile[0][1] + tile[0][2] + tile[0][3];
    const float sstot = tile[0][4] + tile[0][5] + tile[0][6] + tile[0][7];
    const float mu  = stot * (1.0f / DD);
    const float var = sstot * (1.0f / DD) - mu * mu;
    const float inv = rsqrtf(var + 1e-5f);
    const float4 g4 = ((const float4*)g)[t];
    const float4 b4 = ((const float4*)bta)[t];
    ushort4 o;
    o.x = f2bf((v.x - mu) * inv * g4.x + b4.x);
    o.y = f2bf((v.y - mu) * inv * g4.y + b4.y);
    o.z = f2bf((v.z - mu) * inv * g4.z + b4.z);
    o.w = f2bf((v.w - mu) * inv * g4.w + b4.w);
    ((ushort4*)(xn + (size_t)row * DD))[t] = o;
  } else {
    const int wb = blockIdx.x - NROWS;        // 0..1023
    const int z = wb >> 8;                    // matrix id
    const int k0 = (wb & 15) * 64, n0 = ((wb >> 4) & 15) * 64;
    const float* W = (z == 0) ? Wq : (z == 1) ? Wk : (z == 2) ? Wv : Wo;
    ushort* dst = wt + (size_t)z * DD * DD;
    const int tr = t >> 4, tc = (t & 15) * 4;
#pragma unroll
    for (int rr = 0; rr < 64; rr += 16) {
      float4 v = *(const float4*)(W + (size_t)(k0 + rr + tr) * DD + n0 + tc);
      tile[rr + tr][tc + 0] = v.x;
      tile[rr + tr][tc + 1] = v.y;
      tile[rr + tr][tc + 2] = v.z;
      tile[rr + tr][tc + 3] = v.w;
    }
    __syncthreads();
#pragma unroll
    for (int rr = 0; rr < 64; rr += 16) {
      const int n = rr + tr;
      ushort4 o;
      o.x = f2bf(tile[tc + 0][n]);
      o.y = f2bf(tile[tc + 1][n]);
      o.z = f2bf(tile[tc + 2][n]);
      o.w = f2bf(tile[tc + 3][n]);
      *(ushort4*)(dst + (size_t)(n0 + n) * DD + k0 + tc) = o;
    }
  }
}

// ---------------------------------------------------------------------------
// GEMM core. 128x128 tile, 4 waves, BK=32. TRIPLE-buffered global_load_lds
// staging with counted vmcnt(4) (only current tile's loads) + raw s_barrier
// (no vmcnt(0) drain). Swizzle: store-side source pre-swz (t>>3)&3, read-side
// XOR (r16>>1)&3 -> conflict-free b128 frag reads (row bits 1-2, since 64B
// rows already fold row bit 0 into the bank index).
// ---------------------------------------------------------------------------
#define GEMM_CORE(Ag, Bg)                                                     \
  f32x4 acc[4][4];                                                            \
  _Pragma("unroll")                                                           \
  for (int m = 0; m < 4; ++m)                                                 \
    _Pragma("unroll")                                                         \
    for (int n = 0; n < 4; ++n) acc[m][n] = (f32x4){0.f, 0.f, 0.f, 0.f};     \
  const int cs = ((t & 3) * 16) ^ (((t >> 3) & 3) * 16);                      \
  const int fsw = ((r16 >> 1) & 3) * 16;                                      \
  {                                                                           \
    GSTAGE(Ag, Bg, 0, 0);                                                     \
    GSTAGE(Ag, Bg, 1, 32);                                                    \
    int cb = 0;                                                               \
    for (int k0 = 0; k0 < DD; k0 += 32) {                                     \
      __builtin_amdgcn_sched_barrier(0);                                      \
      if (k0 + 32 < DD) {                                                     \
        asm volatile("s_waitcnt vmcnt(4)" ::: "memory");                      \
      } else {                                                                \
        asm volatile("s_waitcnt vmcnt(0)" ::: "memory");                      \
      }                                                                       \
      __builtin_amdgcn_s_barrier();                                           \
      __builtin_amdgcn_sched_barrier(0);                                      \
      if (k0 + 64 < DD) {                                                     \
        int nb = cb + 2; if (nb >= 3) nb -= 3;                                \
        GSTAGE(Ag, Bg, nb, k0 + 64);                                          \
      }                                                                       \
      const char* Ac = (const char*)&As[cb][0][0];                            \
      const char* Bc = (const char*)&Bs[cb][0][0];                            \
      short8 af[4], bf[4];                                                    \
      _Pragma("unroll")                                                       \
      for (int m = 0; m < 4; ++m)                                             \
        af[m] = *(const short8*)(Ac + (wr * 64 + m * 16 + r16) * 64 +         \
                                 ((g * 16) ^ fsw));                           \
      _Pragma("unroll")                                                       \
      for (int n = 0; n < 4; ++n)                                             \
        bf[n] = *(const short8*)(Bc + (wc * 64 + n * 16 + r16) * 64 +         \
                                 ((g * 16) ^ fsw));                           \
      _Pragma("unroll")                                                       \
      for (int m = 0; m < 4; ++m)                                             \
        _Pragma("unroll")                                                     \
        for (int n = 0; n < 4; ++n) acc[m][n] = mfma16(af[m], bf[n], acc[m][n]); \
      cb = (cb + 1 == 3) ? 0 : cb + 1;                                        \
    }                                                                         \
  }

#define GSTAGE(Ag, Bg, buf, k0)                                               \
  {                                                                           \
    _Pragma("unroll")                                                         \
    for (int i = 0; i < 2; ++i) {                                             \
      gload_lds16(Ag + (size_t)(row0 + i * 64 + (t >> 2)) * (DD * 2) +        \
                      (k0) * 2 + cs,                                          \
                  (char*)&As[buf][0][0] + i * 4096 + t * 16);                 \
      gload_lds16(Bg + (size_t)(col0 + i * 64 + (t >> 2)) * (DD * 2) +        \
                      (k0) * 2 + cs,                                          \
                  (char*)&Bs[buf][0][0] + i * 4096 + t * 16);                 \
    }                                                                         \
  }

// Fused QKV projection. Q output is PRE-SCALED by 1/sqrt(64)*log2(e) so the
// attention kernel's scores land directly in the exp2 domain.
__global__ __launch_bounds__(256) void gemm_qkv(
    const ushort* __restrict__ A, const ushort* __restrict__ wt,
    const float* __restrict__ bq, const float* __restrict__ bk,
    const float* __restrict__ bv, ushort* __restrict__ qb,
    ushort* __restrict__ kb, ushort* __restrict__ vt) {
  __shared__ ushort As[3][128][32];
  __shared__ ushort Bs[3][128][32];
  const int t = threadIdx.x;
  const int lane = t & 63;
  const int w = t >> 6, wr = w >> 1, wc = w & 1;
  const int r16 = lane & 15, g = lane >> 4;
  const int row0 = blockIdx.x * 128;
  const int mat = blockIdx.y >> 3;
  const int col0 = (blockIdx.y & 7) * 128;
  const char* Ag = (const char*)A;
  const char* Bg = (const char*)(wt + (size_t)mat * DD * DD);
  const float* bias = (mat == 0) ? bq : (mat == 1) ? bk : bv;
  const float scl = (mat == 0) ? 0.125f * 1.44269504f : 1.0f;

  GEMM_CORE(Ag, Bg)

#pragma unroll
  for (int n = 0; n < 4; ++n) {
    const int c = col0 + wc * 64 + n * 16 + r16;
    const float bc = bias[c];
#pragma unroll
    for (int m = 0; m < 4; ++m) {
      const int rbase = row0 + wr * 64 + m * 16 + g * 4;
      if (mat < 2) {
        ushort* outb = (mat == 0) ? qb : kb;
#pragma unroll
        for (int e = 0; e < 4; ++e)
          outb[(size_t)(rbase + e) * DD + c] = f2bf((acc[m][n][e] + bc) * scl);
      } else {
        uint2 st;
        st.x = cvt_pk_bf16(acc[m][n][0] + bc, acc[m][n][1] + bc);
        st.y = cvt_pk_bf16(acc[m][n][2] + bc, acc[m][n][3] + bc);
        const size_t vrow = (size_t)((rbase >> 11) * HH + (c >> 6)) * DQK + (c & 63);
        *(uint2*)(vt + vrow * SS + (rbase & 2047)) = st;
      }
    }
  }
}

// Output projection: att @ Wo + bo + x -> fp32 out.
__global__ __launch_bounds__(256) void gemm_o(
    const ushort* __restrict__ A, const ushort* __restrict__ Bt,
    const float* __restrict__ bias, const float* __restrict__ resid,
    float* __restrict__ outf) {
  __shared__ ushort As[3][128][32];
  __shared__ ushort Bs[3][128][32];
  const int t = threadIdx.x;
  const int lane = t & 63;
  const int w = t >> 6, wr = w >> 1, wc = w & 1;
  const int r16 = lane & 15, g = lane >> 4;
  const int row0 = blockIdx.x * 128;
  const int col0 = blockIdx.y * 128;
  const char* Ag = (const char*)A;
  const char* Bg = (const char*)Bt;

  GEMM_CORE(Ag, Bg)

#pragma unroll
  for (int n = 0; n < 4; ++n) {
    const int c = col0 + wc * 64 + n * 16 + r16;
    const float bc = bias[c];
#pragma unroll
    for (int m = 0; m < 4; ++m) {
      const int rbase = row0 + wr * 64 + m * 16 + g * 4;
#pragma unroll
      for (int e = 0; e < 4; ++e) {
        const size_t idx = (size_t)(rbase + e) * DD + c;
        outf[idx] = acc[m][n][e] + bc + resid[idx];
      }
    }
  }
}

// ---------------------------------------------------------------------------
// MFMA flash attention (causal). One 64-row q-block per block; 1024 blocks.
// KEY RELABELING: QK^T A-row s of MFMA t2 holds physical key
//   key = (t2&1)*4 + (s&3) + (s>>2)*8 + (t2>>1)*32
// so the C/D output lane (r16,g) holds exactly keys {kc*32+g*8+e} = the PV
// B-fragment layout; P never touches LDS. Swizzle uses row bits {0,1,3}
// (the relabeling maps r16>>2 to row bit 3; bit 2 is t2-constant) so the
// permuted K-reads are conflict-free. Balanced map: bid=[j:2][m:3][bh:5].
// ---------------------------------------------------------------------------
__global__ __launch_bounds__(256) void attn_mfma(const ushort* __restrict__ Q,
                                                 const ushort* __restrict__ K,
                                                 const ushort* __restrict__ Vt,
                                                 ushort* __restrict__ O) {
  __shared__ ushort Ks[2][64][64];  // [buf][key][d]  128B rows, swizzled
  __shared__ ushort Vs[2][64][64];  // [buf][dq][key] 128B rows, swizzled

  const int t = threadIdx.x, lane = t & 63, ww = t >> 6;
  const int r16 = lane & 15, g = lane >> 4;

  const int bid = blockIdx.x;                    // 1024 blocks
  const int xcd = bid & 7;
  const int bh = xcd * 4 + ((bid >> 3) & 3);     // 4 heads per XCD
  const int m = (bid >> 5) & 7;
  const int j = bid >> 8;                        // 0..3
  const int qb = (j == 0) ? (31 - m) : (j == 1) ? m : (j == 2) ? (23 - m) : (8 + m);
  const int b = bh >> 4, h = bh & 15;
  const size_t tokbase = (size_t)b * SS;
  const size_t hoff = (size_t)h * DQK;
  const int q0 = qb * 64 + ww * 16;
  const int nt = qb + 1;

  const int srow = t >> 3;                       // 0..31
  const int scol = (t & 7) * 16;                 // 0..112
  const char* Kb = (const char*)(K + tokbase * DD + hoff);
  const char* Vb = (const char*)(Vt + (size_t)bh * DQK * SS);
  const int sw = ((r16 & 3) | ((r16 >> 1) & 4)) << 4;  // V-read swz, bits {0,1,3}
  const int rlo = (r16 & 3) + ((r16 >> 2) << 3);       // K-row permutation base

#define STAGE(buf, j0)                                                        \
  {                                                                           \
    _Pragma("unroll")                                                         \
    for (int i = 0; i < 2; ++i) {                                             \
      const int R = i * 32 + srow;                                            \
      const int Cs = scol ^ (((R & 3) | ((R >> 1) & 4)) << 4);                \
      gload_lds16(Kb + ((size_t)((j0) + R) * DD) * 2 + Cs,                    \
                  (char*)&Ks[buf][0][0] + i * 4096 + ww * 1024);              \
      gload_lds16(Vb + ((size_t)R * SS + (j0)) * 2 + Cs,                      \
                  (char*)&Vs[buf][0][0] + i * 4096 + ww * 1024);              \
    }                                                                         \
  }

  // Q fragments (B-operand, pre-scaled): col=q=r16, k = kc*32 + g*8 + e
  short8 qf[2];
#pragma unroll
  for (int kc = 0; kc < 2; ++kc)
    qf[kc] = *(const short8*)(Q + (tokbase + q0 + r16) * DD + hoff + kc * 32 + g * 8);

  f32x4 o[4];
#pragma unroll
  for (int dt = 0; dt < 4; ++dt) o[dt] = (f32x4){0.f, 0.f, 0.f, 0.f};
  float rm = -INFINITY, rl = 0.f;                // rl is a per-lane PARTIAL

  STAGE(0, 0);
  int cur = 0;
  for (int tt = 0; tt < nt; ++tt) {
    __builtin_amdgcn_sched_barrier(0);
    asm volatile("s_waitcnt vmcnt(0)" ::: "memory");
    __builtin_amdgcn_s_barrier();
    __builtin_amdgcn_sched_barrier(0);
    if (tt + 1 < nt) STAGE(cur ^ 1, (tt + 1) * 64);

    const char* Kc = (const char*)&Ks[cur][0][0];
    const char* Vc = (const char*)&Vs[cur][0][0];

    // --- QK^T with permuted K-rows: lane (r16,g) of s4[t2] holds physical
    // keys {(t2&1)*4 + r + g*8 + (t2>>1)*32}, q = r16 ---
    f32x4 s4[4];
    __builtin_amdgcn_s_setprio(1);
#pragma unroll
    for (int t2 = 0; t2 < 4; ++t2) {
      const int kk = rlo + (t2 & 1) * 4 + (t2 >> 1) * 32;
      const int sk = ((kk & 3) | ((kk >> 1) & 4)) << 4;
      const int rb = kk * 128;
      const short8 k0 = *(const short8*)(Kc + rb + ((g * 16) ^ sk));
      const short8 k1 = *(const short8*)(Kc + rb + ((64 + g * 16) ^ sk));
      f32x4 s = mfma16(k0, qf[0], (f32x4){0.f, 0.f, 0.f, 0.f});
      s4[t2] = mfma16(k1, qf[1], s);
    }
    __builtin_amdgcn_s_setprio(0);

    if (tt == nt - 1) {                          // mask last tile only
      const int thrl = q0 + r16 - g * 8 - tt * 64;
#pragma unroll
      for (int t2 = 0; t2 < 4; ++t2) {
        const int bb = (t2 & 1) * 4 + (t2 >> 1) * 32;
#pragma unroll
        for (int r = 0; r < 4; ++r)
          s4[t2][r] = (bb + r <= thrl) ? s4[t2][r] : -INFINITY;
      }
    }

    // --- in-lane max over this lane's 16 keys ---
    float mx = fmaxf(
        fmaxf(fmaxf(fmaxf(s4[0][0], s4[0][1]), fmaxf(s4[0][2], s4[0][3])),
              fmaxf(fmaxf(s4[1][0], s4[1][1]), fmaxf(s4[1][2], s4[1][3]))),
        fmaxf(fmaxf(fmaxf(s4[2][0], s4[2][1]), fmaxf(s4[2][2], s4[2][3])),
              fmaxf(fmaxf(s4[3][0], s4[3][1]), fmaxf(s4[3][2], s4[3][3]))));

    // --- defer-max: rescale only when some lane's max grew past rm+8 ---
    if (!__all(mx - rm <= 8.f)) {
      float mf = fmaxf(mx, __shfl_xor(mx, 16));
      mf = fmaxf(mf, __shfl_xor(mf, 32));        // column max over 64 keys
      const float mn = fmaxf(rm, mf);
      const float sc = __builtin_amdgcn_exp2f(rm - mn);
      rl *= sc;
#pragma unroll
      for (int dt = 0; dt < 4; ++dt) o[dt] *= sc;
      rm = mn;
    }

    // --- P = exp2(S - rm), packed IN-LANE directly to PV B-frags ---
    union { unsigned u[4]; short8 s; } pbu[2];
#pragma unroll
    for (int t2 = 0; t2 < 4; ++t2) {
      const float p0 = __builtin_amdgcn_exp2f(s4[t2][0] - rm);
      const float p1 = __builtin_amdgcn_exp2f(s4[t2][1] - rm);
      const float p2 = __builtin_amdgcn_exp2f(s4[t2][2] - rm);
      const float p3 = __builtin_amdgcn_exp2f(s4[t2][3] - rm);
      rl += (p0 + p1) + (p2 + p3);
      pbu[t2 >> 1].u[(t2 & 1) * 2 + 0] = cvt_pk_bf16(p0, p1);
      pbu[t2 >> 1].u[(t2 & 1) * 2 + 1] = cvt_pk_bf16(p2, p3);
    }

    // --- PV: O[dq][q] ---
    __builtin_amdgcn_s_setprio(1);
#pragma unroll
    for (int kc = 0; kc < 2; ++kc) {
#pragma unroll
      for (int dt = 0; dt < 4; ++dt) {
        const short8 vf = *(const short8*)(Vc + (dt * 16 + r16) * 128 +
                                           ((kc * 64 + g * 16) ^ sw));
        o[dt] = mfma16(vf, pbu[kc].s, o[dt]);
      }
    }
    __builtin_amdgcn_s_setprio(0);
    cur ^= 1;
  }
#undef STAGE

  // --- cross-lane l-reduction, once ---
  rl += __shfl_xor(rl, 16);
  rl += __shfl_xor(rl, 32);
  const float inv = 1.0f / rl;
#pragma unroll
  for (int dt = 0; dt < 4; ++dt) {
    uint2 st;
    st.x = cvt_pk_bf16(o[dt][0] * inv, o[dt][1] * inv);
    st.y = cvt_pk_bf16(o[dt][2] * inv, o[dt][3] * inv);
    *(uint2*)(O + (tokbase + q0 + r16) * DD + hoff + dt * 16 + g * 4) = st;
  }
}

// ---------------------------------------------------------------------------
// Launch: prep (LN + wtrans fused) -> fused QKV GEMM -> attn -> O-GEMM.
// ws: xn 8MB | q 8MB | k 8MB | vt 8MB | att 8MB | wt 16MB  (56MB)
// ---------------------------------------------------------------------------
extern "C" void kernel_launch(void* const* d_in, const int* in_sizes, int n_in,
                              void* d_out, int out_size, void* d_ws, size_t ws_size,
                              hipStream_t stream) {
  const float* x    = (const float*)d_in[0];
  const float* ln_g = (const float*)d_in[1];
  const float* ln_b = (const float*)d_in[2];
  const float* Wq   = (const float*)d_in[3];
  const float* bq   = (const float*)d_in[4];
  const float* Wk   = (const float*)d_in[5];
  const float* bk   = (const float*)d_in[6];
  const float* Wv   = (const float*)d_in[7];
  const float* bv   = (const float*)d_in[8];
  const float* Wo   = (const float*)d_in[9];
  const float* bo   = (const float*)d_in[10];
  float* out = (float*)d_out;

  ushort* ws  = (ushort*)d_ws;
  ushort* xn  = ws;
  ushort* qb  = xn + NE;
  ushort* kb  = qb + NE;
  ushort* vt  = kb + NE;
  ushort* ab  = vt + NE;
  ushort* wt  = ab + NE;               // 4 x [1024][1024] bf16
  ushort* wot = wt + (size_t)3 * DD * DD;

  prep<<<NROWS + 1024, 256, 0, stream>>>(x, ln_g, ln_b, xn, Wq, Wk, Wv, Wo, wt);

  gemm_qkv<<<dim3(NROWS / 128, 24), 256, 0, stream>>>(xn, wt, bq, bk, bv,
                                                      qb, kb, vt);

  attn_mfma<<<BB * HH * (SS / 64), 256, 0, stream>>>(qb, kb, vt, ab);

  gemm_o<<<dim3(NROWS / 128, DD / 128), 256, 0, stream>>>(ab, wot, bo, x, out);
}